// Round 1
// baseline (308.186 us; speedup 1.0000x reference)
//
#include <hip/hip_runtime.h>
#include <hip/hip_bf16.h>
#include <cstdint>
#include <cstddef>

// ---------------------------------------------------------------------------
// MultiHeadAttention: x[B,S,E] -> causal MHA -> out[B,S,E]
// B=2 S=2048 E=1024 H=16 D=64.  bf16 MFMA path (threshold is bf16-level).
// Pipeline: convert -> qkv gemm (scatter to Q/K/V [BH,S,D] bf16) ->
//           flash attention -> out gemm (fp32 + bias).
// Workspace: 40 MB (xb reused as attn output buffer).
// ---------------------------------------------------------------------------

typedef unsigned short u16;
typedef __attribute__((ext_vector_type(8))) short short8;
typedef __attribute__((ext_vector_type(4))) float floatx4;

#define MFMA16(a, b, c) __builtin_amdgcn_mfma_f32_16x16x32_bf16((a), (b), (c), 0, 0, 0)

static __device__ __forceinline__ u16 f2b(float f) {
    union { float f; uint32_t u; } v; v.f = f;
    uint32_t r = (v.u + 0x7fffu + ((v.u >> 16) & 1u)) >> 16;  // RNE
    return (u16)r;
}

// ---------------- conversion kernels ----------------

__global__ __launch_bounds__(256) void k_f32_to_bf16(const float* __restrict__ src,
                                                     u16* __restrict__ dst, int n8) {
    int g = blockIdx.x * 256 + threadIdx.x;
    if (g >= n8) return;
    const float4* s = (const float4*)src + (size_t)g * 2;
    float4 f0 = s[0];
    float4 f1 = s[1];
    alignas(16) u16 r[8] = {f2b(f0.x), f2b(f0.y), f2b(f0.z), f2b(f0.w),
                            f2b(f1.x), f2b(f1.y), f2b(f1.z), f2b(f1.w)};
    *(uint4*)(dst + (size_t)g * 8) = *(const uint4*)r;
}

// src[R][C] fp32  ->  dst[C][R] bf16   (tiled transpose, block (32,8))
__global__ __launch_bounds__(256) void k_transpose_to_bf16(const float* __restrict__ src,
                                                           u16* __restrict__ dst,
                                                           int R, int C) {
    __shared__ float t[32][33];
    int tx = threadIdx.x, ty = threadIdx.y;
    int c0 = blockIdx.x * 32, r0 = blockIdx.y * 32;
#pragma unroll
    for (int i = 0; i < 4; ++i)
        t[ty + i * 8][tx] = src[(size_t)(r0 + ty + i * 8) * C + c0 + tx];
    __syncthreads();
#pragma unroll
    for (int i = 0; i < 4; ++i)
        dst[(size_t)(c0 + ty + i * 8) * R + r0 + tx] = f2b(t[tx][ty + i * 8]);
}

// ---------------- GEMM kernels ----------------
// C[M,N] = A[M,K] * B[K,N] (+bias). A row-major bf16 [M,1024].
// Bt = B transposed, bf16 [N,1024] (K contiguous).
// Block: 256 thr = 4 waves, tile 64x64, BK=64, wave -> 32x32 (2x2 MFMA tiles).
// LDS rows padded to 72 elems (144 B) -> 2-way-max bank aliasing (free).

__global__ __launch_bounds__(256) void k_qkv_gemm(const u16* __restrict__ A,
                                                  const u16* __restrict__ Bt,
                                                  const float* __restrict__ bias,
                                                  u16* __restrict__ Qb,
                                                  u16* __restrict__ Kb,
                                                  u16* __restrict__ Vb) {
    const int K = 1024;
    __shared__ u16 As[64 * 72];
    __shared__ u16 Bs[64 * 72];
    int tid = threadIdx.x;
    int w = tid >> 6, lane = tid & 63, quad = lane >> 4, l16 = lane & 15;
    int wm = w >> 1, wn = w & 1;
    int m0 = blockIdx.y * 64, n0 = blockIdx.x * 64;
    floatx4 acc[2][2] = {};

    for (int kt = 0; kt < K / 64; ++kt) {
#pragma unroll
        for (int i = 0; i < 2; ++i) {
            int g = tid + i * 256;
            int row = g >> 3, cg = (g & 7) * 8;
            *(uint4*)&As[row * 72 + cg] = *(const uint4*)&A[(size_t)(m0 + row) * K + kt * 64 + cg];
            *(uint4*)&Bs[row * 72 + cg] = *(const uint4*)&Bt[(size_t)(n0 + row) * K + kt * 64 + cg];
        }
        __syncthreads();
#pragma unroll
        for (int ks = 0; ks < 2; ++ks) {
            short8 a0 = *(const short8*)&As[(wm * 32 + l16) * 72 + ks * 32 + quad * 8];
            short8 a1 = *(const short8*)&As[(wm * 32 + 16 + l16) * 72 + ks * 32 + quad * 8];
            short8 b0 = *(const short8*)&Bs[(wn * 32 + l16) * 72 + ks * 32 + quad * 8];
            short8 b1 = *(const short8*)&Bs[(wn * 32 + 16 + l16) * 72 + ks * 32 + quad * 8];
            acc[0][0] = MFMA16(a0, b0, acc[0][0]);
            acc[0][1] = MFMA16(a0, b1, acc[0][1]);
            acc[1][0] = MFMA16(a1, b0, acc[1][0]);
            acc[1][1] = MFMA16(a1, b1, acc[1][1]);
        }
        __syncthreads();
    }

    // epilogue: bias + scatter into Q/K/V [BH=32][S=2048][D=64] bf16
    int which = n0 >> 10;  // n0 is 64-aligned, 64 | 1024 -> uniform per block
    u16* dst = which == 0 ? Qb : (which == 1 ? Kb : Vb);
#pragma unroll
    for (int mt = 0; mt < 2; ++mt)
#pragma unroll
        for (int nt = 0; nt < 2; ++nt)
#pragma unroll
            for (int r = 0; r < 4; ++r) {
                int m_abs = m0 + wm * 32 + mt * 16 + quad * 4 + r;
                int n_abs = n0 + wn * 32 + nt * 16 + l16;
                float val = acc[mt][nt][r] + bias[n_abs];
                int e = n_abs & 1023, h = e >> 6, d = e & 63;
                int b = m_abs >> 11, s = m_abs & 2047;
                dst[((size_t)(b * 16 + h) * 2048 + s) * 64 + d] = f2b(val);
            }
}

__global__ __launch_bounds__(256) void k_out_gemm(const u16* __restrict__ A,
                                                  const u16* __restrict__ Bt,
                                                  const float* __restrict__ bias,
                                                  float* __restrict__ out) {
    const int K = 1024;
    __shared__ u16 As[64 * 72];
    __shared__ u16 Bs[64 * 72];
    int tid = threadIdx.x;
    int w = tid >> 6, lane = tid & 63, quad = lane >> 4, l16 = lane & 15;
    int wm = w >> 1, wn = w & 1;
    int m0 = blockIdx.y * 64, n0 = blockIdx.x * 64;
    floatx4 acc[2][2] = {};

    for (int kt = 0; kt < K / 64; ++kt) {
#pragma unroll
        for (int i = 0; i < 2; ++i) {
            int g = tid + i * 256;
            int row = g >> 3, cg = (g & 7) * 8;
            *(uint4*)&As[row * 72 + cg] = *(const uint4*)&A[(size_t)(m0 + row) * K + kt * 64 + cg];
            *(uint4*)&Bs[row * 72 + cg] = *(const uint4*)&Bt[(size_t)(n0 + row) * K + kt * 64 + cg];
        }
        __syncthreads();
#pragma unroll
        for (int ks = 0; ks < 2; ++ks) {
            short8 a0 = *(const short8*)&As[(wm * 32 + l16) * 72 + ks * 32 + quad * 8];
            short8 a1 = *(const short8*)&As[(wm * 32 + 16 + l16) * 72 + ks * 32 + quad * 8];
            short8 b0 = *(const short8*)&Bs[(wn * 32 + l16) * 72 + ks * 32 + quad * 8];
            short8 b1 = *(const short8*)&Bs[(wn * 32 + 16 + l16) * 72 + ks * 32 + quad * 8];
            acc[0][0] = MFMA16(a0, b0, acc[0][0]);
            acc[0][1] = MFMA16(a0, b1, acc[0][1]);
            acc[1][0] = MFMA16(a1, b0, acc[1][0]);
            acc[1][1] = MFMA16(a1, b1, acc[1][1]);
        }
        __syncthreads();
    }

#pragma unroll
    for (int mt = 0; mt < 2; ++mt)
#pragma unroll
        for (int nt = 0; nt < 2; ++nt)
#pragma unroll
            for (int r = 0; r < 4; ++r) {
                int m_abs = m0 + wm * 32 + mt * 16 + quad * 4 + r;
                int n_abs = n0 + wn * 32 + nt * 16 + l16;
                out[(size_t)m_abs * 1024 + n_abs] = acc[mt][nt][r] + bias[n_abs];
            }
}

// ---------------- flash attention ----------------
// grid (32 q-tiles, 32 bh). block 256 = 4 waves; wave w owns Q rows
// [q0+16w, q0+16w+16). Q frags in registers; K tile + V^T tile in LDS;
// P round-trips through LDS for C-layout -> A-layout transform.

__global__ __launch_bounds__(256) void k_attn(const u16* __restrict__ Qb,
                                              const u16* __restrict__ Kb,
                                              const u16* __restrict__ Vb,
                                              u16* __restrict__ attnb) {
    __shared__ u16 Ks[64 * 72];        // [key][d]
    __shared__ u16 Vt[64 * 72];        // [d][key]
    __shared__ u16 Ps[4 * 16 * 72];    // [wave strip row][key]
    int tid = threadIdx.x;
    int w = tid >> 6, lane = tid & 63, quad = lane >> 4, l16 = lane & 15;
    int bh = blockIdx.y, qt = blockIdx.x;
    int q0 = qt * 64;
    const u16* Qp = Qb + (size_t)bh * 2048 * 64;
    const u16* Kp = Kb + (size_t)bh * 2048 * 64;
    const u16* Vp = Vb + (size_t)bh * 2048 * 64;

    int qrow = q0 + w * 16 + l16;
    short8 qf0 = *(const short8*)&Qp[(size_t)qrow * 64 + quad * 8];
    short8 qf1 = *(const short8*)&Qp[(size_t)qrow * 64 + 32 + quad * 8];

    floatx4 accO[4] = {};
    float m_run[4], l_run[4];
#pragma unroll
    for (int r = 0; r < 4; ++r) { m_run[r] = -__builtin_inff(); l_run[r] = 0.f; }

    for (int kt = 0; kt <= qt; ++kt) {
        // stage K tile [64 keys][64 d]
#pragma unroll
        for (int i = 0; i < 2; ++i) {
            int g = tid + i * 256;
            int row = g >> 3, cg = (g & 7) * 8;
            *(uint4*)&Ks[row * 72 + cg] = *(const uint4*)&Kp[(size_t)(kt * 64 + row) * 64 + cg];
        }
        // stage V^T tile [64 d][64 keys]: lane owns d=lane, 8 keys -> uint4 LDS write
#pragma unroll
        for (int i = 0; i < 2; ++i) {
            int g = tid + i * 256;
            int d = g & 63, kg = (g >> 6) * 8;
            alignas(16) u16 tmp[8];
#pragma unroll
            for (int j = 0; j < 8; ++j)
                tmp[j] = Vp[(size_t)(kt * 64 + kg + j) * 64 + d];
            *(uint4*)&Vt[d * 72 + kg] = *(const uint4*)tmp;
        }
        __syncthreads();

        // S = Q K^T   (wave strip: 16 q-rows x 64 keys)
        floatx4 sa[4] = {};
#pragma unroll
        for (int nt = 0; nt < 4; ++nt) {
            short8 kfa = *(const short8*)&Ks[(nt * 16 + l16) * 72 + quad * 8];
            short8 kfb = *(const short8*)&Ks[(nt * 16 + l16) * 72 + 32 + quad * 8];
            sa[nt] = MFMA16(qf0, kfa, sa[nt]);
            sa[nt] = MFMA16(qf1, kfb, sa[nt]);
        }

        // scale + causal mask (only diagonal tile needs masking)
        float p[4][4];
        bool diag = (kt == qt);
#pragma unroll
        for (int nt = 0; nt < 4; ++nt)
#pragma unroll
            for (int r = 0; r < 4; ++r) {
                float s = sa[nt][r] * 0.125f;  // 1/sqrt(64)
                if (diag) {
                    int k_abs = kt * 64 + nt * 16 + l16;
                    int q_abs = q0 + w * 16 + quad * 4 + r;
                    if (k_abs > q_abs) s = -__builtin_inff();
                }
                p[nt][r] = s;
            }

        // online softmax per q-row (row lives on 16 lanes of one quad)
        float alpha[4];
#pragma unroll
        for (int r = 0; r < 4; ++r) {
            float v = fmaxf(fmaxf(p[0][r], p[1][r]), fmaxf(p[2][r], p[3][r]));
#pragma unroll
            for (int off = 1; off < 16; off <<= 1)
                v = fmaxf(v, __shfl_xor(v, off, 16));
            float m_new = fmaxf(m_run[r], v);
            alpha[r] = __expf(m_run[r] - m_new);
            float rs = 0.f;
#pragma unroll
            for (int nt = 0; nt < 4; ++nt) {
                float e = __expf(p[nt][r] - m_new);
                p[nt][r] = e;
                rs += e;
            }
#pragma unroll
            for (int off = 1; off < 16; off <<= 1)
                rs += __shfl_xor(rs, off, 16);
            l_run[r] = l_run[r] * alpha[r] + rs;
            m_run[r] = m_new;
        }
#pragma unroll
        for (int dt = 0; dt < 4; ++dt)
#pragma unroll
            for (int r = 0; r < 4; ++r)
                accO[dt][r] *= alpha[r];

        // P (C-layout) -> LDS -> A-layout for PV
#pragma unroll
        for (int nt = 0; nt < 4; ++nt)
#pragma unroll
            for (int r = 0; r < 4; ++r)
                Ps[(w * 16 + quad * 4 + r) * 72 + nt * 16 + l16] = f2b(p[nt][r]);
        __syncthreads();

        // O += P V
#pragma unroll
        for (int ks = 0; ks < 2; ++ks) {
            short8 pf = *(const short8*)&Ps[(w * 16 + l16) * 72 + ks * 32 + quad * 8];
#pragma unroll
            for (int dt = 0; dt < 4; ++dt) {
                short8 vf = *(const short8*)&Vt[(dt * 16 + l16) * 72 + ks * 32 + quad * 8];
                accO[dt] = MFMA16(pf, vf, accO[dt]);
            }
        }
        __syncthreads();  // protect Ks/Vt/Ps before next staging
    }

    // epilogue: O/l -> attnb [B][S][E] bf16
    int b = bh >> 4, h = bh & 15;
#pragma unroll
    for (int r = 0; r < 4; ++r) {
        float inv = 1.f / l_run[r];
        int q_abs = q0 + w * 16 + quad * 4 + r;
        size_t base = ((size_t)(b * 2048 + q_abs)) * 1024 + h * 64;
#pragma unroll
        for (int dt = 0; dt < 4; ++dt)
            attnb[base + dt * 16 + l16] = f2b(accO[dt][r] * inv);
    }
}

// ---------------- launch ----------------

extern "C" void kernel_launch(void* const* d_in, const int* in_sizes, int n_in,
                              void* d_out, int out_size, void* d_ws, size_t ws_size,
                              hipStream_t stream) {
    const float* x     = (const float*)d_in[0];
    const float* W_qkv = (const float*)d_in[1];
    const float* b_qkv = (const float*)d_in[2];
    const float* W_out = (const float*)d_in[3];
    const float* b_out = (const float*)d_in[4];
    float* out = (float*)d_out;

    char* p = (char*)d_ws;
    u16* xb    = (u16*)p; p += (size_t)4096 * 1024 * 2;     // 8 MB (reused as attn out)
    u16* wqkvT = (u16*)p; p += (size_t)3072 * 1024 * 2;     // 6 MB
    u16* woutT = (u16*)p; p += (size_t)1024 * 1024 * 2;     // 2 MB
    u16* Qb    = (u16*)p; p += (size_t)32 * 2048 * 64 * 2;  // 8 MB
    u16* Kb    = (u16*)p; p += (size_t)32 * 2048 * 64 * 2;  // 8 MB
    u16* Vb    = (u16*)p; p += (size_t)32 * 2048 * 64 * 2;  // 8 MB
    u16* attnb = xb;  // xb is dead after k_qkv_gemm

    k_f32_to_bf16<<<(4096 * 1024 / 8) / 256, 256, 0, stream>>>(x, xb, 4096 * 1024 / 8);
    dim3 tb(32, 8);
    k_transpose_to_bf16<<<dim3(3072 / 32, 1024 / 32), tb, 0, stream>>>(W_qkv, wqkvT, 1024, 3072);
    k_transpose_to_bf16<<<dim3(1024 / 32, 1024 / 32), tb, 0, stream>>>(W_out, woutT, 1024, 1024);
    k_qkv_gemm<<<dim3(48, 64), 256, 0, stream>>>(xb, wqkvT, b_qkv, Qb, Kb, Vb);
    k_attn<<<dim3(32, 32), 256, 0, stream>>>(Qb, Kb, Vb, attnb);
    k_out_gemm<<<dim3(16, 64), 256, 0, stream>>>(attnb, woutT, b_out, out);
}

// Round 2
// 235.690 us; speedup vs baseline: 1.3076x; 1.3076x over previous
//
#include <hip/hip_runtime.h>
#include <hip/hip_bf16.h>
#include <cstdint>
#include <cstddef>

// ---------------------------------------------------------------------------
// MultiHeadAttention  B=2 S=2048 E=1024 H=16 D=64 causal, bf16 MFMA path.
// conv -> qkv gemm128 (scatter Q*0.125 / K to [bh][s][d], V to Vt[bh][d][s])
//      -> flash attn (dbuf async K/Vt staging, paired q-tiles) -> out gemm128.
// Workspace: 40 MB. attnb aliases xb.
// ---------------------------------------------------------------------------

typedef unsigned short u16;
typedef __attribute__((ext_vector_type(8))) short short8;
typedef __attribute__((ext_vector_type(4))) float floatx4;

#define MFMA16(a, b, c) __builtin_amdgcn_mfma_f32_16x16x32_bf16((a), (b), (c), 0, 0, 0)

static __device__ __forceinline__ u16 f2b(float f) {
    union { float f; uint32_t u; } v; v.f = f;
    return (u16)((v.u + 0x7fffu + ((v.u >> 16) & 1u)) >> 16);  // RNE
}

// async 16B global->LDS. lds ptr must be wave-uniform; HW adds lane*16.
static __device__ __forceinline__ void async_cp16(const u16* g, u16* lds_wave_base) {
    __builtin_amdgcn_global_load_lds((__attribute__((address_space(1))) void*)g,
                                     (__attribute__((address_space(3))) void*)lds_wave_base,
                                     16, 0, 0);
}

// ---------------- conversion kernels ----------------

__global__ __launch_bounds__(256) void k_f32_to_bf16(const float* __restrict__ src,
                                                     u16* __restrict__ dst, int n8) {
    int g = blockIdx.x * 256 + threadIdx.x;
    if (g >= n8) return;
    const float4* s = (const float4*)src + (size_t)g * 2;
    float4 f0 = s[0];
    float4 f1 = s[1];
    alignas(16) u16 r[8] = {f2b(f0.x), f2b(f0.y), f2b(f0.z), f2b(f0.w),
                            f2b(f1.x), f2b(f1.y), f2b(f1.z), f2b(f1.w)};
    *(uint4*)(dst + (size_t)g * 8) = *(const uint4*)r;
}

// src[R][C] fp32 -> dst[C][R] bf16
__global__ __launch_bounds__(256) void k_transpose_to_bf16(const float* __restrict__ src,
                                                           u16* __restrict__ dst,
                                                           int R, int C) {
    __shared__ float t[32][33];
    int tx = threadIdx.x, ty = threadIdx.y;
    int c0 = blockIdx.x * 32, r0 = blockIdx.y * 32;
#pragma unroll
    for (int i = 0; i < 4; ++i)
        t[ty + i * 8][tx] = src[(size_t)(r0 + ty + i * 8) * C + c0 + tx];
    __syncthreads();
#pragma unroll
    for (int i = 0; i < 4; ++i)
        dst[(size_t)(c0 + ty + i * 8) * R + r0 + tx] = f2b(t[tx][ty + i * 8]);
}

// ---------------- 128x128 GEMM (m97 structure + XOR swizzle) ----------------
// C[M,N] = A[M,1024] * Bt[N,1024]^T (+bias). 256 thr = 4 waves (2x2), each
// wave 64x64 = 4x4 MFMA tiles. BK=64. LDS rows of 64 u16 (8 chunks of 16B),
// chunk c of row r stored at slot c^(r&7)  -> conflict-free ds_read_b128.

__global__ __launch_bounds__(256) void k_qkv_gemm(const u16* __restrict__ A,
                                                  const u16* __restrict__ Bt,
                                                  const float* __restrict__ bias,
                                                  u16* __restrict__ Qb,
                                                  u16* __restrict__ Kb,
                                                  u16* __restrict__ Vtb) {
    __shared__ __align__(16) u16 As[128 * 64];
    __shared__ __align__(16) u16 Bs[128 * 64];
    int tid = threadIdx.x;
    int w = tid >> 6, lane = tid & 63, quad = lane >> 4, l16 = lane & 15;
    int wm = w >> 1, wn = w & 1;
    int m0 = blockIdx.y * 128, n0 = blockIdx.x * 128;
    int wb8 = (tid & ~63) * 8;
    floatx4 acc[4][4] = {};

    for (int kt = 0; kt < 16; ++kt) {
#pragma unroll
        for (int i = 0; i < 4; ++i) {
            int f = i * 256 + tid;
            int r = f >> 3, c = (f & 7) ^ (r & 7);
            async_cp16(&A[(size_t)(m0 + r) * 1024 + kt * 64 + c * 8], &As[i * 2048 + wb8]);
        }
#pragma unroll
        for (int i = 0; i < 4; ++i) {
            int f = i * 256 + tid;
            int r = f >> 3, c = (f & 7) ^ (r & 7);
            async_cp16(&Bt[(size_t)(n0 + r) * 1024 + kt * 64 + c * 8], &Bs[i * 2048 + wb8]);
        }
        __syncthreads();
#pragma unroll
        for (int ks = 0; ks < 2; ++ks) {
            short8 af[4], bf[4];
            int sw = l16 & 7;
#pragma unroll
            for (int mt = 0; mt < 4; ++mt)
                af[mt] = *(const short8*)&As[((wm * 64 + mt * 16 + l16) * 8 + ((ks * 4 + quad) ^ sw)) * 8];
#pragma unroll
            for (int nt = 0; nt < 4; ++nt)
                bf[nt] = *(const short8*)&Bs[((wn * 64 + nt * 16 + l16) * 8 + ((ks * 4 + quad) ^ sw)) * 8];
#pragma unroll
            for (int mt = 0; mt < 4; ++mt)
#pragma unroll
                for (int nt = 0; nt < 4; ++nt)
                    acc[mt][nt] = MFMA16(af[mt], bf[nt], acc[mt][nt]);
        }
        __syncthreads();
    }

    int region = n0 >> 10;  // 0=Q 1=K 2=V (tiles never straddle regions)
#pragma unroll
    for (int mt = 0; mt < 4; ++mt)
#pragma unroll
        for (int nt = 0; nt < 4; ++nt)
#pragma unroll
            for (int r = 0; r < 4; ++r) {
                int m_abs = m0 + wm * 64 + mt * 16 + quad * 4 + r;
                int n_abs = n0 + wn * 64 + nt * 16 + l16;
                float val = acc[mt][nt][r] + bias[n_abs];
                int e = n_abs & 1023, h = e >> 6, d = e & 63;
                int b = m_abs >> 11, s = m_abs & 2047;
                int bh = b * 16 + h;
                if (region == 0)
                    Qb[((size_t)bh * 2048 + s) * 64 + d] = f2b(val * 0.125f);  // pre-scale 1/sqrt(64)
                else if (region == 1)
                    Kb[((size_t)bh * 2048 + s) * 64 + d] = f2b(val);
                else
                    Vtb[((size_t)bh * 64 + d) * 2048 + s] = f2b(val);  // V stored transposed
            }
}

__global__ __launch_bounds__(256) void k_out_gemm(const u16* __restrict__ A,
                                                  const u16* __restrict__ Bt,
                                                  const float* __restrict__ bias,
                                                  float* __restrict__ out) {
    __shared__ __align__(16) u16 As[128 * 64];
    __shared__ __align__(16) u16 Bs[128 * 64];
    int tid = threadIdx.x;
    int w = tid >> 6, lane = tid & 63, quad = lane >> 4, l16 = lane & 15;
    int wm = w >> 1, wn = w & 1;
    int m0 = blockIdx.y * 128, n0 = blockIdx.x * 128;
    int wb8 = (tid & ~63) * 8;
    floatx4 acc[4][4] = {};

    for (int kt = 0; kt < 16; ++kt) {
#pragma unroll
        for (int i = 0; i < 4; ++i) {
            int f = i * 256 + tid;
            int r = f >> 3, c = (f & 7) ^ (r & 7);
            async_cp16(&A[(size_t)(m0 + r) * 1024 + kt * 64 + c * 8], &As[i * 2048 + wb8]);
        }
#pragma unroll
        for (int i = 0; i < 4; ++i) {
            int f = i * 256 + tid;
            int r = f >> 3, c = (f & 7) ^ (r & 7);
            async_cp16(&Bt[(size_t)(n0 + r) * 1024 + kt * 64 + c * 8], &Bs[i * 2048 + wb8]);
        }
        __syncthreads();
#pragma unroll
        for (int ks = 0; ks < 2; ++ks) {
            short8 af[4], bf[4];
            int sw = l16 & 7;
#pragma unroll
            for (int mt = 0; mt < 4; ++mt)
                af[mt] = *(const short8*)&As[((wm * 64 + mt * 16 + l16) * 8 + ((ks * 4 + quad) ^ sw)) * 8];
#pragma unroll
            for (int nt = 0; nt < 4; ++nt)
                bf[nt] = *(const short8*)&Bs[((wn * 64 + nt * 16 + l16) * 8 + ((ks * 4 + quad) ^ sw)) * 8];
#pragma unroll
            for (int mt = 0; mt < 4; ++mt)
#pragma unroll
                for (int nt = 0; nt < 4; ++nt)
                    acc[mt][nt] = MFMA16(af[mt], bf[nt], acc[mt][nt]);
        }
        __syncthreads();
    }

#pragma unroll
    for (int mt = 0; mt < 4; ++mt)
#pragma unroll
        for (int nt = 0; nt < 4; ++nt)
#pragma unroll
            for (int r = 0; r < 4; ++r) {
                int m_abs = m0 + wm * 64 + mt * 16 + quad * 4 + r;
                int n_abs = n0 + wn * 64 + nt * 16 + l16;
                out[(size_t)m_abs * 1024 + n_abs] = acc[mt][nt][r] + bias[n_abs];
            }
}

// ---------------- flash attention ----------------
// grid (16 pairs, 32 bh), block 256 = 4 waves. Block processes q-tile pr then
// 31-pr (constant 33 K-tile iterations -> balanced). K/Vt tiles staged with
// async global_load_lds into double-buffered LDS; ONE barrier per iteration.
// P bounce through per-wave LDS slice (wave-local: lgkmcnt only, no barrier).

__global__ __launch_bounds__(256) void k_attn(const u16* __restrict__ Qb,
                                              const u16* __restrict__ Kb,
                                              const u16* __restrict__ Vtb,
                                              u16* __restrict__ attnb) {
    __shared__ __align__(16) u16 K0s[64 * 64];
    __shared__ __align__(16) u16 K1s[64 * 64];
    __shared__ __align__(16) u16 V0s[64 * 64];
    __shared__ __align__(16) u16 V1s[64 * 64];
    __shared__ __align__(16) u16 Ps[4 * 16 * 72];
    int tid = threadIdx.x;
    int w = tid >> 6, lane = tid & 63, quad = lane >> 4, l16 = lane & 15;
    int bh = blockIdx.y, pr = blockIdx.x;
    const u16* Qp = Qb + (size_t)bh * 2048 * 64;
    const u16* Kp = Kb + (size_t)bh * 2048 * 64;
    const u16* Vp = Vtb + (size_t)bh * 64 * 2048;
    u16* Pw = &Ps[w * 16 * 72];

    auto stage = [&](u16* Ks, u16* Vs, int kt) {
        int k0 = kt * 64;
#pragma unroll
        for (int i = 0; i < 2; ++i) {
            int f = i * 256 + tid;
            int r = f >> 3, c = (f & 7) ^ (r & 7);
            async_cp16(&Kp[(size_t)(k0 + r) * 64 + c * 8], &Ks[i * 2048 + (tid & ~63) * 8]);
        }
#pragma unroll
        for (int i = 0; i < 2; ++i) {
            int f = i * 256 + tid;
            int r = f >> 3, c = (f & 7) ^ (r & 7);
            async_cp16(&Vp[(size_t)r * 2048 + k0 + c * 8], &Vs[i * 2048 + (tid & ~63) * 8]);
        }
    };

    for (int half = 0; half < 2; ++half) {
        int qt = half ? (31 - pr) : pr;
        int q0 = qt * 64;
        int qrow = q0 + w * 16 + l16;
        short8 qf0 = *(const short8*)&Qp[(size_t)qrow * 64 + quad * 8];
        short8 qf1 = *(const short8*)&Qp[(size_t)qrow * 64 + 32 + quad * 8];
        floatx4 accO[4] = {};
        float m_run[4], l_run[4];
#pragma unroll
        for (int r = 0; r < 4; ++r) { m_run[r] = -__builtin_inff(); l_run[r] = 0.f; }
        int nkt = qt + 1;

        auto step = [&](const u16* Ks, const u16* Vs, int kt) {
            int sw = l16 & 7;
            floatx4 sa[4] = {};
#pragma unroll
            for (int nt = 0; nt < 4; ++nt) {
                int rb = (nt * 16 + l16) * 8;
                short8 kfa = *(const short8*)&Ks[(rb + (quad ^ sw)) * 8];
                short8 kfb = *(const short8*)&Ks[(rb + ((4 + quad) ^ sw)) * 8];
                sa[nt] = MFMA16(qf0, kfa, sa[nt]);
                sa[nt] = MFMA16(qf1, kfb, sa[nt]);
            }
            bool diag = (kt == qt);
            float p[4][4];
#pragma unroll
            for (int nt = 0; nt < 4; ++nt)
#pragma unroll
                for (int r = 0; r < 4; ++r) {
                    float s = sa[nt][r];
                    if (diag && (kt * 64 + nt * 16 + l16 > q0 + w * 16 + quad * 4 + r))
                        s = -__builtin_inff();
                    p[nt][r] = s;
                }
            float alpha[4];
#pragma unroll
            for (int r = 0; r < 4; ++r) {
                float v = fmaxf(fmaxf(p[0][r], p[1][r]), fmaxf(p[2][r], p[3][r]));
#pragma unroll
                for (int off = 1; off < 16; off <<= 1)
                    v = fmaxf(v, __shfl_xor(v, off, 16));
                float m_new = fmaxf(m_run[r], v);
                alpha[r] = __expf(m_run[r] - m_new);
                float rs = 0.f;
#pragma unroll
                for (int nt = 0; nt < 4; ++nt) {
                    float e = __expf(p[nt][r] - m_new);
                    p[nt][r] = e;
                    rs += e;
                }
#pragma unroll
                for (int off = 1; off < 16; off <<= 1)
                    rs += __shfl_xor(rs, off, 16);
                l_run[r] = l_run[r] * alpha[r] + rs;
                m_run[r] = m_new;
            }
#pragma unroll
            for (int dt = 0; dt < 4; ++dt)
#pragma unroll
                for (int r = 0; r < 4; ++r)
                    accO[dt][r] *= alpha[r];
            // P: C-layout -> A-layout via per-wave LDS slice (wave-local)
#pragma unroll
            for (int nt = 0; nt < 4; ++nt)
#pragma unroll
                for (int r = 0; r < 4; ++r)
                    Pw[(quad * 4 + r) * 72 + nt * 16 + l16] = f2b(p[nt][r]);
            asm volatile("s_waitcnt lgkmcnt(0)" ::: "memory");
#pragma unroll
            for (int ks = 0; ks < 2; ++ks) {
                short8 pf = *(const short8*)&Pw[l16 * 72 + ks * 32 + quad * 8];
#pragma unroll
                for (int dt = 0; dt < 4; ++dt) {
                    int rb = (dt * 16 + l16) * 8;
                    short8 vf = *(const short8*)&Vs[(rb + ((ks * 4 + quad) ^ sw)) * 8];
                    accO[dt] = MFMA16(pf, vf, accO[dt]);
                }
            }
        };

        stage(K0s, V0s, 0);
        __syncthreads();
        for (int kt = 0; kt < nkt; kt += 2) {
            if (kt + 1 < nkt) stage(K1s, V1s, kt + 1);  // async prefetch
            step(K0s, V0s, kt);
            __syncthreads();
            if (kt + 1 < nkt) {
                if (kt + 2 < nkt) stage(K0s, V0s, kt + 2);
                step(K1s, V1s, kt + 1);
                __syncthreads();
            }
        }

        int b = bh >> 4, h = bh & 15;
#pragma unroll
        for (int r = 0; r < 4; ++r) {
            float inv = 1.f / l_run[r];
            int q_abs = q0 + w * 16 + quad * 4 + r;
            size_t base = ((size_t)(b * 2048 + q_abs)) * 1024 + h * 64;
#pragma unroll
            for (int dt = 0; dt < 4; ++dt)
                attnb[base + dt * 16 + l16] = f2b(accO[dt][r] * inv);
        }
    }
}

// ---------------- launch ----------------

extern "C" void kernel_launch(void* const* d_in, const int* in_sizes, int n_in,
                              void* d_out, int out_size, void* d_ws, size_t ws_size,
                              hipStream_t stream) {
    const float* x     = (const float*)d_in[0];
    const float* W_qkv = (const float*)d_in[1];
    const float* b_qkv = (const float*)d_in[2];
    const float* W_out = (const float*)d_in[3];
    const float* b_out = (const float*)d_in[4];
    float* out = (float*)d_out;

    char* p = (char*)d_ws;
    u16* xb    = (u16*)p; p += (size_t)4096 * 1024 * 2;     // 8 MB (reused as attn out)
    u16* wqkvT = (u16*)p; p += (size_t)3072 * 1024 * 2;     // 6 MB
    u16* woutT = (u16*)p; p += (size_t)1024 * 1024 * 2;     // 2 MB
    u16* Qb    = (u16*)p; p += (size_t)32 * 2048 * 64 * 2;  // 8 MB (pre-scaled by 0.125)
    u16* Kb    = (u16*)p; p += (size_t)32 * 2048 * 64 * 2;  // 8 MB
    u16* Vtb   = (u16*)p; p += (size_t)32 * 64 * 2048 * 2;  // 8 MB [bh][d][s]
    u16* attnb = xb;  // xb dead after k_qkv_gemm

    k_f32_to_bf16<<<(4096 * 1024 / 8) / 256, 256, 0, stream>>>(x, xb, 4096 * 1024 / 8);
    dim3 tb(32, 8);
    k_transpose_to_bf16<<<dim3(3072 / 32, 1024 / 32), tb, 0, stream>>>(W_qkv, wqkvT, 1024, 3072);
    k_transpose_to_bf16<<<dim3(1024 / 32, 1024 / 32), tb, 0, stream>>>(W_out, woutT, 1024, 1024);
    k_qkv_gemm<<<dim3(24, 32), 256, 0, stream>>>(xb, wqkvT, b_qkv, Qb, Kb, Vtb);
    k_attn<<<dim3(16, 32), 256, 0, stream>>>(Qb, Kb, Vtb, attnb);
    k_out_gemm<<<dim3(8, 32), 256, 0, stream>>>(attnb, woutT, b_out, out);
}

// Round 3
// 219.453 us; speedup vs baseline: 1.4043x; 1.0740x over previous
//
#include <hip/hip_runtime.h>
#include <hip/hip_bf16.h>
#include <cstdint>
#include <cstddef>

// ---------------------------------------------------------------------------
// MultiHeadAttention  B=2 S=2048 E=1024 H=16 D=64 causal, bf16 MFMA path.
// conv -> qkv gemm128 (scatter Q*0.125*log2e / K to [bh][s][d], V^T to
// [bh][d][s]) -> flash attn (S^T trick: no LDS P-bounce, K=16 PV MFMA)
// -> out gemm128.  Workspace: 40 MB. attnb aliases xb.
// ---------------------------------------------------------------------------

typedef unsigned short u16;
typedef __attribute__((ext_vector_type(8))) short short8;
typedef __attribute__((ext_vector_type(4))) short short4v;
typedef __attribute__((ext_vector_type(4))) float floatx4;

#define MFMA16(a, b, c) __builtin_amdgcn_mfma_f32_16x16x32_bf16((a), (b), (c), 0, 0, 0)

#if __has_builtin(__builtin_amdgcn_mfma_f32_16x16x16_bf16)
#define PV_MFMA(a, b, c) __builtin_amdgcn_mfma_f32_16x16x16_bf16((a), (b), (c), 0, 0, 0)
#elif __has_builtin(__builtin_amdgcn_mfma_f32_16x16x16bf16_1k)
#define PV_MFMA(a, b, c) __builtin_amdgcn_mfma_f32_16x16x16bf16_1k((a), (b), (c), 0, 0, 0)
#else
static __device__ __forceinline__ floatx4 pv_mfma_asm(short4v a, short4v b, floatx4 c) {
    asm volatile("v_mfma_f32_16x16x16_bf16 %0, %1, %2, %0" : "+v"(c) : "v"(a), "v"(b));
    return c;
}
#define PV_MFMA(a, b, c) pv_mfma_asm((a), (b), (c))
#endif

#if __has_builtin(__builtin_amdgcn_exp2f)
#define EXP2(x) __builtin_amdgcn_exp2f(x)
#else
#define EXP2(x) exp2f(x)
#endif

#define QSCALE 0.18033688011f  // 0.125 * log2(e): softmax in exp2 domain

static __device__ __forceinline__ u16 f2b(float f) {
    union { float f; uint32_t u; } v; v.f = f;
    return (u16)((v.u + 0x7fffu + ((v.u >> 16) & 1u)) >> 16);  // RNE
}

// pack 2 floats -> 2 bf16 (round-half-up) in one u32 via v_perm
static __device__ __forceinline__ uint32_t pkbf(float lo, float hi) {
    union { float f; uint32_t u; } a, b; a.f = lo; b.f = hi;
    return __builtin_amdgcn_perm(b.u + 0x8000u, a.u + 0x8000u, 0x07060302u);
}

// async 16B global->LDS. lds ptr must be wave-uniform; HW adds lane*16.
static __device__ __forceinline__ void async_cp16(const u16* g, u16* lds_wave_base) {
    __builtin_amdgcn_global_load_lds((__attribute__((address_space(1))) void*)g,
                                     (__attribute__((address_space(3))) void*)lds_wave_base,
                                     16, 0, 0);
}

// ---------------- conversion kernels ----------------

__global__ __launch_bounds__(256) void k_f32_to_bf16(const float* __restrict__ src,
                                                     u16* __restrict__ dst, int n8) {
    int g = blockIdx.x * 256 + threadIdx.x;
    if (g >= n8) return;
    const float4* s = (const float4*)src + (size_t)g * 2;
    float4 f0 = s[0];
    float4 f1 = s[1];
    alignas(16) u16 r[8] = {f2b(f0.x), f2b(f0.y), f2b(f0.z), f2b(f0.w),
                            f2b(f1.x), f2b(f1.y), f2b(f1.z), f2b(f1.w)};
    *(uint4*)(dst + (size_t)g * 8) = *(const uint4*)r;
}

// src[R][C] fp32 -> dst[C][R] bf16
__global__ __launch_bounds__(256) void k_transpose_to_bf16(const float* __restrict__ src,
                                                           u16* __restrict__ dst,
                                                           int R, int C) {
    __shared__ float t[32][33];
    int tx = threadIdx.x, ty = threadIdx.y;
    int c0 = blockIdx.x * 32, r0 = blockIdx.y * 32;
#pragma unroll
    for (int i = 0; i < 4; ++i)
        t[ty + i * 8][tx] = src[(size_t)(r0 + ty + i * 8) * C + c0 + tx];
    __syncthreads();
#pragma unroll
    for (int i = 0; i < 4; ++i)
        dst[(size_t)(c0 + ty + i * 8) * R + r0 + tx] = f2b(t[tx][ty + i * 8]);
}

// ---------------- 128x128 GEMM (m97 structure + XOR swizzle) ----------------

__global__ __launch_bounds__(256) void k_qkv_gemm(const u16* __restrict__ A,
                                                  const u16* __restrict__ Bt,
                                                  const float* __restrict__ bias,
                                                  u16* __restrict__ Qb,
                                                  u16* __restrict__ Kb,
                                                  u16* __restrict__ Vtb) {
    __shared__ __align__(16) u16 As[128 * 64];
    __shared__ __align__(16) u16 Bs[128 * 64];
    int tid = threadIdx.x;
    int w = tid >> 6, lane = tid & 63, quad = lane >> 4, l16 = lane & 15;
    int wm = w >> 1, wn = w & 1;
    int m0 = blockIdx.y * 128, n0 = blockIdx.x * 128;
    int wb8 = (tid & ~63) * 8;
    floatx4 acc[4][4] = {};

    for (int kt = 0; kt < 16; ++kt) {
#pragma unroll
        for (int i = 0; i < 4; ++i) {
            int f = i * 256 + tid;
            int r = f >> 3, c = (f & 7) ^ (r & 7);
            async_cp16(&A[(size_t)(m0 + r) * 1024 + kt * 64 + c * 8], &As[i * 2048 + wb8]);
        }
#pragma unroll
        for (int i = 0; i < 4; ++i) {
            int f = i * 256 + tid;
            int r = f >> 3, c = (f & 7) ^ (r & 7);
            async_cp16(&Bt[(size_t)(n0 + r) * 1024 + kt * 64 + c * 8], &Bs[i * 2048 + wb8]);
        }
        __syncthreads();
#pragma unroll
        for (int ks = 0; ks < 2; ++ks) {
            short8 af[4], bf[4];
            int sw = l16 & 7;
#pragma unroll
            for (int mt = 0; mt < 4; ++mt)
                af[mt] = *(const short8*)&As[((wm * 64 + mt * 16 + l16) * 8 + ((ks * 4 + quad) ^ sw)) * 8];
#pragma unroll
            for (int nt = 0; nt < 4; ++nt)
                bf[nt] = *(const short8*)&Bs[((wn * 64 + nt * 16 + l16) * 8 + ((ks * 4 + quad) ^ sw)) * 8];
#pragma unroll
            for (int mt = 0; mt < 4; ++mt)
#pragma unroll
                for (int nt = 0; nt < 4; ++nt)
                    acc[mt][nt] = MFMA16(af[mt], bf[nt], acc[mt][nt]);
        }
        __syncthreads();
    }

    int region = n0 >> 10;  // 0=Q 1=K 2=V
    if (region == 2) {
        // V^T scatter, packed: 4 consecutive s per (mt,nt) -> one uint2 store
#pragma unroll
        for (int mt = 0; mt < 4; ++mt)
#pragma unroll
            for (int nt = 0; nt < 4; ++nt) {
                int n_abs = n0 + wn * 64 + nt * 16 + l16;
                int e = n_abs & 1023, h = e >> 6, d = e & 63;
                float vb = bias[n_abs];
                int mrow = m0 + wm * 64 + mt * 16 + quad * 4;
                int b = mrow >> 11, s0 = mrow & 2047;
                uint2 val;
                val.x = pkbf(acc[mt][nt][0] + vb, acc[mt][nt][1] + vb);
                val.y = pkbf(acc[mt][nt][2] + vb, acc[mt][nt][3] + vb);
                *(uint2*)&Vtb[((size_t)(b * 16 + h) * 64 + d) * 2048 + s0] = val;
            }
    } else {
        u16* dst = region == 0 ? Qb : Kb;
        float scl = region == 0 ? QSCALE : 1.0f;
#pragma unroll
        for (int mt = 0; mt < 4; ++mt)
#pragma unroll
            for (int nt = 0; nt < 4; ++nt)
#pragma unroll
                for (int r = 0; r < 4; ++r) {
                    int m_abs = m0 + wm * 64 + mt * 16 + quad * 4 + r;
                    int n_abs = n0 + wn * 64 + nt * 16 + l16;
                    float val = (acc[mt][nt][r] + bias[n_abs]) * scl;
                    int e = n_abs & 1023, h = e >> 6, d = e & 63;
                    int b = m_abs >> 11, s = m_abs & 2047;
                    dst[((size_t)(b * 16 + h) * 2048 + s) * 64 + d] = f2b(val);
                }
    }
}

__global__ __launch_bounds__(256) void k_out_gemm(const u16* __restrict__ A,
                                                  const u16* __restrict__ Bt,
                                                  const float* __restrict__ bias,
                                                  float* __restrict__ out) {
    __shared__ __align__(16) u16 As[128 * 64];
    __shared__ __align__(16) u16 Bs[128 * 64];
    int tid = threadIdx.x;
    int w = tid >> 6, lane = tid & 63, quad = lane >> 4, l16 = lane & 15;
    int wm = w >> 1, wn = w & 1;
    int m0 = blockIdx.y * 128, n0 = blockIdx.x * 128;
    int wb8 = (tid & ~63) * 8;
    floatx4 acc[4][4] = {};

    for (int kt = 0; kt < 16; ++kt) {
#pragma unroll
        for (int i = 0; i < 4; ++i) {
            int f = i * 256 + tid;
            int r = f >> 3, c = (f & 7) ^ (r & 7);
            async_cp16(&A[(size_t)(m0 + r) * 1024 + kt * 64 + c * 8], &As[i * 2048 + wb8]);
        }
#pragma unroll
        for (int i = 0; i < 4; ++i) {
            int f = i * 256 + tid;
            int r = f >> 3, c = (f & 7) ^ (r & 7);
            async_cp16(&Bt[(size_t)(n0 + r) * 1024 + kt * 64 + c * 8], &Bs[i * 2048 + wb8]);
        }
        __syncthreads();
#pragma unroll
        for (int ks = 0; ks < 2; ++ks) {
            short8 af[4], bf[4];
            int sw = l16 & 7;
#pragma unroll
            for (int mt = 0; mt < 4; ++mt)
                af[mt] = *(const short8*)&As[((wm * 64 + mt * 16 + l16) * 8 + ((ks * 4 + quad) ^ sw)) * 8];
#pragma unroll
            for (int nt = 0; nt < 4; ++nt)
                bf[nt] = *(const short8*)&Bs[((wn * 64 + nt * 16 + l16) * 8 + ((ks * 4 + quad) ^ sw)) * 8];
#pragma unroll
            for (int mt = 0; mt < 4; ++mt)
#pragma unroll
                for (int nt = 0; nt < 4; ++nt)
                    acc[mt][nt] = MFMA16(af[mt], bf[nt], acc[mt][nt]);
        }
        __syncthreads();
    }

#pragma unroll
    for (int mt = 0; mt < 4; ++mt)
#pragma unroll
        for (int nt = 0; nt < 4; ++nt)
#pragma unroll
            for (int r = 0; r < 4; ++r) {
                int m_abs = m0 + wm * 64 + mt * 16 + quad * 4 + r;
                int n_abs = n0 + wn * 64 + nt * 16 + l16;
                out[(size_t)m_abs * 1024 + n_abs] = acc[mt][nt][r] + bias[n_abs];
            }
}

// ---------------- flash attention (S^T layout, no P LDS bounce) -------------
// grid (32 qt-swizzled, 32 bh), block 256 = 4 waves; wave w owns q-rows
// [q0+16w, q0+16w+16). QK^T with swapped operands -> lane holds one q-row
// (l16) x 16 keys (nt,quad*4+r). Softmax: in-lane reduce + 2 shfl (xor 16,32).
// P regs ARE the A-frag of the K=16 PV MFMA; V^T B-frags read b64 from LDS.
// LDS 32 KB -> 4 blocks/CU resident (grid 1024 all co-resident).

__global__ __launch_bounds__(256, 4) void k_attn(const u16* __restrict__ Qb,
                                                 const u16* __restrict__ Kb,
                                                 const u16* __restrict__ Vtb,
                                                 u16* __restrict__ attnb) {
    __shared__ __align__(16) u16 K0s[64 * 64];
    __shared__ __align__(16) u16 K1s[64 * 64];
    __shared__ __align__(16) u16 V0s[64 * 64];
    __shared__ __align__(16) u16 V1s[64 * 64];
    int tid = threadIdx.x;
    int w = tid >> 6, lane = tid & 63, quad = lane >> 4, l16 = lane & 15;
    int bh = blockIdx.y;
    int qt = (blockIdx.x * 13) & 31;  // swizzle: mixes heavy/light blocks per CU
    int q0 = qt * 64;
    const u16* Qp = Qb + (size_t)bh * 2048 * 64;
    const u16* Kp = Kb + (size_t)bh * 2048 * 64;
    const u16* Vp = Vtb + (size_t)bh * 64 * 2048;

    int qrow = q0 + w * 16 + l16;
    short8 qf0 = *(const short8*)&Qp[(size_t)qrow * 64 + quad * 8];
    short8 qf1 = *(const short8*)&Qp[(size_t)qrow * 64 + 32 + quad * 8];

    floatx4 accO[4] = {};
    float m_run = -__builtin_inff(), l_run = 0.f;
    int nkt = qt + 1;
    int sw = l16 & 7;

    auto stage = [&](u16* Ks, u16* Vs, int kt) {
        int k0 = kt * 64;
#pragma unroll
        for (int i = 0; i < 2; ++i) {
            int f = i * 256 + tid;
            int r = f >> 3, c = (f & 7) ^ (r & 7);
            async_cp16(&Kp[(size_t)(k0 + r) * 64 + c * 8], &Ks[i * 2048 + (tid & ~63) * 8]);
        }
#pragma unroll
        for (int i = 0; i < 2; ++i) {
            int f = i * 256 + tid;
            int r = f >> 3, c = (f & 7) ^ (r & 7);
            async_cp16(&Vp[(size_t)r * 2048 + k0 + c * 8], &Vs[i * 2048 + (tid & ~63) * 8]);
        }
    };

    auto step = [&](const u16* Ks, const u16* Vs, int kt) {
        // S^T = K Q^T : lane holds S[qrow=l16][key = kt*64 + nt*16 + quad*4 + r]
        floatx4 sa[4] = {};
#pragma unroll
        for (int nt = 0; nt < 4; ++nt) {
            int rb = (nt * 16 + l16) * 8;
            short8 kfa = *(const short8*)&Ks[(rb + (quad ^ sw)) * 8];
            short8 kfb = *(const short8*)&Ks[(rb + ((4 + quad) ^ sw)) * 8];
            sa[nt] = MFMA16(kfa, qf0, sa[nt]);
            sa[nt] = MFMA16(kfb, qf1, sa[nt]);
        }
        if (kt == qt) {  // diagonal tile: causal mask (wave-uniform branch)
            int q_abs = q0 + w * 16 + l16;
#pragma unroll
            for (int nt = 0; nt < 4; ++nt)
#pragma unroll
                for (int r = 0; r < 4; ++r)
                    if (kt * 64 + nt * 16 + quad * 4 + r > q_abs)
                        sa[nt][r] = -__builtin_inff();
        }
        // online softmax, exp2 domain; row = fixed per lane, replicated x4 quads
        float v = sa[0][0];
#pragma unroll
        for (int nt = 0; nt < 4; ++nt)
#pragma unroll
            for (int r = 0; r < 4; ++r) v = fmaxf(v, sa[nt][r]);
        v = fmaxf(v, __shfl_xor(v, 16));
        v = fmaxf(v, __shfl_xor(v, 32));
        float m_new = fmaxf(m_run, v);
        float alpha = EXP2(m_run - m_new);
        float p[4][4];
        float rs = 0.f;
#pragma unroll
        for (int nt = 0; nt < 4; ++nt)
#pragma unroll
            for (int r = 0; r < 4; ++r) {
                float e = EXP2(sa[nt][r] - m_new);
                p[nt][r] = e;
                rs += e;
            }
        rs += __shfl_xor(rs, 16);
        rs += __shfl_xor(rs, 32);
        l_run = l_run * alpha + rs;
        m_run = m_new;
        // rescale O (O is in C-layout: row=quad*4+r needs alpha of that q-row)
        float al[4];
#pragma unroll
        for (int r = 0; r < 4; ++r) al[r] = __shfl(alpha, quad * 4 + r, 16);
#pragma unroll
        for (int dt = 0; dt < 4; ++dt)
#pragma unroll
            for (int r = 0; r < 4; ++r) accO[dt][r] *= al[r];
        // P regs are already the K=16 A-frag: pack and multiply into O
#pragma unroll
        for (int nt = 0; nt < 4; ++nt) {
            union { uint2 u; short4v s; } pf;
            pf.u.x = pkbf(p[nt][0], p[nt][1]);
            pf.u.y = pkbf(p[nt][2], p[nt][3]);
#pragma unroll
            for (int dt = 0; dt < 4; ++dt) {
                int row = dt * 16 + l16;
                int chunk = nt * 2 + (quad >> 1);
                const char* vb = (const char*)Vs + row * 128 + ((chunk ^ (row & 7)) * 16) + (quad & 1) * 8;
                short4v vf = *(const short4v*)vb;
                accO[dt] = PV_MFMA(pf.s, vf, accO[dt]);
            }
        }
    };

    stage(K0s, V0s, 0);
    __syncthreads();
    for (int kt = 0; kt < nkt; kt += 2) {
        if (kt + 1 < nkt) stage(K1s, V1s, kt + 1);  // async prefetch
        step(K0s, V0s, kt);
        __syncthreads();
        if (kt + 1 < nkt) {
            if (kt + 2 < nkt) stage(K0s, V0s, kt + 2);
            step(K1s, V1s, kt + 1);
            __syncthreads();
        }
    }

    // epilogue: O (C-layout) / l -> attnb [B][S][E] bf16
    int b = bh >> 4, h = bh & 15;
    float lbc[4];
#pragma unroll
    for (int r = 0; r < 4; ++r) lbc[r] = __shfl(l_run, quad * 4 + r, 16);
#pragma unroll
    for (int r = 0; r < 4; ++r) {
        float inv = 1.f / lbc[r];
        int q_abs = q0 + w * 16 + quad * 4 + r;
        size_t base = ((size_t)(b * 2048 + q_abs)) * 1024 + h * 64;
#pragma unroll
        for (int dt = 0; dt < 4; ++dt)
            attnb[base + dt * 16 + l16] = f2b(accO[dt][r] * inv);
    }
}

// ---------------- launch ----------------

extern "C" void kernel_launch(void* const* d_in, const int* in_sizes, int n_in,
                              void* d_out, int out_size, void* d_ws, size_t ws_size,
                              hipStream_t stream) {
    const float* x     = (const float*)d_in[0];
    const float* W_qkv = (const float*)d_in[1];
    const float* b_qkv = (const float*)d_in[2];
    const float* W_out = (const float*)d_in[3];
    const float* b_out = (const float*)d_in[4];
    float* out = (float*)d_out;

    char* p = (char*)d_ws;
    u16* xb    = (u16*)p; p += (size_t)4096 * 1024 * 2;     // 8 MB (reused as attn out)
    u16* wqkvT = (u16*)p; p += (size_t)3072 * 1024 * 2;     // 6 MB
    u16* woutT = (u16*)p; p += (size_t)1024 * 1024 * 2;     // 2 MB
    u16* Qb    = (u16*)p; p += (size_t)32 * 2048 * 64 * 2;  // 8 MB (pre-scaled, exp2 domain)
    u16* Kb    = (u16*)p; p += (size_t)32 * 2048 * 64 * 2;  // 8 MB
    u16* Vtb   = (u16*)p; p += (size_t)32 * 64 * 2048 * 2;  // 8 MB [bh][d][s]
    u16* attnb = xb;  // xb dead after k_qkv_gemm

    k_f32_to_bf16<<<(4096 * 1024 / 8) / 256, 256, 0, stream>>>(x, xb, 4096 * 1024 / 8);
    dim3 tb(32, 8);
    k_transpose_to_bf16<<<dim3(3072 / 32, 1024 / 32), tb, 0, stream>>>(W_qkv, wqkvT, 1024, 3072);
    k_transpose_to_bf16<<<dim3(1024 / 32, 1024 / 32), tb, 0, stream>>>(W_out, woutT, 1024, 1024);
    k_qkv_gemm<<<dim3(24, 32), 256, 0, stream>>>(xb, wqkvT, b_qkv, Qb, Kb, Vtb);
    k_attn<<<dim3(32, 32), 256, 0, stream>>>(Qb, Kb, Vtb, attnb);
    k_out_gemm<<<dim3(8, 32), 256, 0, stream>>>(attnb, woutT, b_out, out);
}

// Round 4
// 194.094 us; speedup vs baseline: 1.5878x; 1.1307x over previous
//
#include <hip/hip_runtime.h>
#include <hip/hip_bf16.h>
#include <cstdint>
#include <cstddef>

// ---------------------------------------------------------------------------
// MultiHeadAttention  B=2 S=2048 E=1024 H=16 D=64 causal, bf16 MFMA path.
// conv -> qkv gemm128 -> flash attn (ring-4 LDS, raw s_barrier + manual
// vmcnt(8), depth-3 prefetch, paired q-tiles, XCD-local bh) -> out gemm 64x128.
// ---------------------------------------------------------------------------

typedef unsigned short u16;
typedef __attribute__((ext_vector_type(8))) short short8;
typedef __attribute__((ext_vector_type(4))) short short4v;
typedef __attribute__((ext_vector_type(4))) float floatx4;

#define MFMA16(a, b, c) __builtin_amdgcn_mfma_f32_16x16x32_bf16((a), (b), (c), 0, 0, 0)

#if __has_builtin(__builtin_amdgcn_mfma_f32_16x16x16_bf16)
#define PV_MFMA(a, b, c) __builtin_amdgcn_mfma_f32_16x16x16_bf16((a), (b), (c), 0, 0, 0)
#elif __has_builtin(__builtin_amdgcn_mfma_f32_16x16x16bf16_1k)
#define PV_MFMA(a, b, c) __builtin_amdgcn_mfma_f32_16x16x16bf16_1k((a), (b), (c), 0, 0, 0)
#else
static __device__ __forceinline__ floatx4 pv_mfma_asm(short4v a, short4v b, floatx4 c) {
    asm volatile("v_mfma_f32_16x16x16_bf16 %0, %1, %2, %0" : "+v"(c) : "v"(a), "v"(b));
    return c;
}
#define PV_MFMA(a, b, c) pv_mfma_asm((a), (b), (c))
#endif

#if __has_builtin(__builtin_amdgcn_exp2f)
#define EXP2(x) __builtin_amdgcn_exp2f(x)
#else
#define EXP2(x) exp2f(x)
#endif

#define QSCALE 0.18033688011f  // 0.125 * log2(e)

static __device__ __forceinline__ u16 f2b(float f) {
    union { float f; uint32_t u; } v; v.f = f;
    return (u16)((v.u + 0x7fffu + ((v.u >> 16) & 1u)) >> 16);  // RNE
}

static __device__ __forceinline__ uint32_t pkbf(float lo, float hi) {
    union { float f; uint32_t u; } a, b; a.f = lo; b.f = hi;
    return __builtin_amdgcn_perm(b.u + 0x8000u, a.u + 0x8000u, 0x07060302u);
}

static __device__ __forceinline__ void async_cp16(const u16* g, u16* lds_wave_base) {
    __builtin_amdgcn_global_load_lds((__attribute__((address_space(1))) void*)g,
                                     (__attribute__((address_space(3))) void*)lds_wave_base,
                                     16, 0, 0);
}

// ---------------- conversion kernels ----------------

__global__ __launch_bounds__(256) void k_f32_to_bf16(const float* __restrict__ src,
                                                     u16* __restrict__ dst, int n8) {
    int g = blockIdx.x * 256 + threadIdx.x;
    if (g >= n8) return;
    const float4* s = (const float4*)src + (size_t)g * 2;
    float4 f0 = s[0];
    float4 f1 = s[1];
    alignas(16) u16 r[8] = {f2b(f0.x), f2b(f0.y), f2b(f0.z), f2b(f0.w),
                            f2b(f1.x), f2b(f1.y), f2b(f1.z), f2b(f1.w)};
    *(uint4*)(dst + (size_t)g * 8) = *(const uint4*)r;
}

__global__ __launch_bounds__(256) void k_transpose_to_bf16(const float* __restrict__ src,
                                                           u16* __restrict__ dst,
                                                           int R, int C) {
    __shared__ float t[32][33];
    int tx = threadIdx.x, ty = threadIdx.y;
    int c0 = blockIdx.x * 32, r0 = blockIdx.y * 32;
#pragma unroll
    for (int i = 0; i < 4; ++i)
        t[ty + i * 8][tx] = src[(size_t)(r0 + ty + i * 8) * C + c0 + tx];
    __syncthreads();
#pragma unroll
    for (int i = 0; i < 4; ++i)
        dst[(size_t)(c0 + ty + i * 8) * R + r0 + tx] = f2b(t[tx][ty + i * 8]);
}

// ---------------- qkv GEMM 128x128 (unchanged structure) ----------------

__global__ __launch_bounds__(256) void k_qkv_gemm(const u16* __restrict__ A,
                                                  const u16* __restrict__ Bt,
                                                  const float* __restrict__ bias,
                                                  u16* __restrict__ Qb,
                                                  u16* __restrict__ Kb,
                                                  u16* __restrict__ Vtb) {
    __shared__ __align__(16) u16 As[128 * 64];
    __shared__ __align__(16) u16 Bs[128 * 64];
    int tid = threadIdx.x;
    int w = tid >> 6, lane = tid & 63, quad = lane >> 4, l16 = lane & 15;
    int wm = w >> 1, wn = w & 1;
    int m0 = blockIdx.y * 128, n0 = blockIdx.x * 128;
    int wb8 = (tid & ~63) * 8;
    floatx4 acc[4][4] = {};

    for (int kt = 0; kt < 16; ++kt) {
#pragma unroll
        for (int i = 0; i < 4; ++i) {
            int f = i * 256 + tid;
            int r = f >> 3, c = (f & 7) ^ (r & 7);
            async_cp16(&A[(size_t)(m0 + r) * 1024 + kt * 64 + c * 8], &As[i * 2048 + wb8]);
        }
#pragma unroll
        for (int i = 0; i < 4; ++i) {
            int f = i * 256 + tid;
            int r = f >> 3, c = (f & 7) ^ (r & 7);
            async_cp16(&Bt[(size_t)(n0 + r) * 1024 + kt * 64 + c * 8], &Bs[i * 2048 + wb8]);
        }
        __syncthreads();
#pragma unroll
        for (int ks = 0; ks < 2; ++ks) {
            short8 af[4], bf[4];
            int sw = l16 & 7;
#pragma unroll
            for (int mt = 0; mt < 4; ++mt)
                af[mt] = *(const short8*)&As[((wm * 64 + mt * 16 + l16) * 8 + ((ks * 4 + quad) ^ sw)) * 8];
#pragma unroll
            for (int nt = 0; nt < 4; ++nt)
                bf[nt] = *(const short8*)&Bs[((wn * 64 + nt * 16 + l16) * 8 + ((ks * 4 + quad) ^ sw)) * 8];
#pragma unroll
            for (int mt = 0; mt < 4; ++mt)
#pragma unroll
                for (int nt = 0; nt < 4; ++nt)
                    acc[mt][nt] = MFMA16(af[mt], bf[nt], acc[mt][nt]);
        }
        __syncthreads();
    }

    int region = n0 >> 10;  // 0=Q 1=K 2=V
    if (region == 2) {
#pragma unroll
        for (int mt = 0; mt < 4; ++mt)
#pragma unroll
            for (int nt = 0; nt < 4; ++nt) {
                int n_abs = n0 + wn * 64 + nt * 16 + l16;
                int e = n_abs & 1023, h = e >> 6, d = e & 63;
                float vb = bias[n_abs];
                int mrow = m0 + wm * 64 + mt * 16 + quad * 4;
                int b = mrow >> 11, s0 = mrow & 2047;
                uint2 val;
                val.x = pkbf(acc[mt][nt][0] + vb, acc[mt][nt][1] + vb);
                val.y = pkbf(acc[mt][nt][2] + vb, acc[mt][nt][3] + vb);
                *(uint2*)&Vtb[((size_t)(b * 16 + h) * 64 + d) * 2048 + s0] = val;
            }
    } else {
        u16* dst = region == 0 ? Qb : Kb;
        float scl = region == 0 ? QSCALE : 1.0f;
#pragma unroll
        for (int mt = 0; mt < 4; ++mt)
#pragma unroll
            for (int nt = 0; nt < 4; ++nt)
#pragma unroll
                for (int r = 0; r < 4; ++r) {
                    int m_abs = m0 + wm * 64 + mt * 16 + quad * 4 + r;
                    int n_abs = n0 + wn * 64 + nt * 16 + l16;
                    float val = (acc[mt][nt][r] + bias[n_abs]) * scl;
                    int e = n_abs & 1023, h = e >> 6, d = e & 63;
                    int b = m_abs >> 11, s = m_abs & 2047;
                    dst[((size_t)(b * 16 + h) * 2048 + s) * 64 + d] = f2b(val);
                }
    }
}

// ---------------- out GEMM 64M x 128N (grid 512 = 2 blocks/CU) -------------

__global__ __launch_bounds__(256) void k_out_gemm(const u16* __restrict__ A,
                                                  const u16* __restrict__ Bt,
                                                  const float* __restrict__ bias,
                                                  float* __restrict__ out) {
    __shared__ __align__(16) u16 As[64 * 64];
    __shared__ __align__(16) u16 Bs[128 * 64];
    int tid = threadIdx.x;
    int w = tid >> 6, lane = tid & 63, quad = lane >> 4, l16 = lane & 15;
    int wm = w >> 1, wn = w & 1;
    int m0 = blockIdx.y * 64, n0 = blockIdx.x * 128;
    int wb8 = (tid & ~63) * 8;
    floatx4 acc[2][4] = {};

    for (int kt = 0; kt < 16; ++kt) {
#pragma unroll
        for (int i = 0; i < 2; ++i) {
            int f = i * 256 + tid;
            int r = f >> 3, c = (f & 7) ^ (r & 7);
            async_cp16(&A[(size_t)(m0 + r) * 1024 + kt * 64 + c * 8], &As[i * 2048 + wb8]);
        }
#pragma unroll
        for (int i = 0; i < 4; ++i) {
            int f = i * 256 + tid;
            int r = f >> 3, c = (f & 7) ^ (r & 7);
            async_cp16(&Bt[(size_t)(n0 + r) * 1024 + kt * 64 + c * 8], &Bs[i * 2048 + wb8]);
        }
        __syncthreads();
#pragma unroll
        for (int ks = 0; ks < 2; ++ks) {
            short8 af[2], bf[4];
            int sw = l16 & 7;
#pragma unroll
            for (int mt = 0; mt < 2; ++mt)
                af[mt] = *(const short8*)&As[((wm * 32 + mt * 16 + l16) * 8 + ((ks * 4 + quad) ^ sw)) * 8];
#pragma unroll
            for (int nt = 0; nt < 4; ++nt)
                bf[nt] = *(const short8*)&Bs[((wn * 64 + nt * 16 + l16) * 8 + ((ks * 4 + quad) ^ sw)) * 8];
#pragma unroll
            for (int mt = 0; mt < 2; ++mt)
#pragma unroll
                for (int nt = 0; nt < 4; ++nt)
                    acc[mt][nt] = MFMA16(af[mt], bf[nt], acc[mt][nt]);
        }
        __syncthreads();
    }

#pragma unroll
    for (int mt = 0; mt < 2; ++mt)
#pragma unroll
        for (int nt = 0; nt < 4; ++nt)
#pragma unroll
            for (int r = 0; r < 4; ++r) {
                int m_abs = m0 + wm * 32 + mt * 16 + quad * 4 + r;
                int n_abs = n0 + wn * 64 + nt * 16 + l16;
                out[(size_t)m_abs * 1024 + n_abs] = acc[mt][nt][r] + bias[n_abs];
            }
}

// ---------------- flash attention: ring-4 + raw barrier pipeline ------------
// grid 512 (1D): bh = (L&7)*4 + (L>>3)&3 (4 heads per XCD -> K/V L2-resident),
// pair (pr, 31-pr) -> flat sequence of 33 tiles. Ring of 4 LDS slots (64 KB),
// depth-3 prefetch; per-iter: s_waitcnt vmcnt(8) (oldest stage done) + raw
// s_barrier. Stage always issues 4 loads (clamped idx) -> uniform vmcnt count.

__global__ __launch_bounds__(256, 2) void k_attn(const u16* __restrict__ Qb,
                                                 const u16* __restrict__ Kb,
                                                 const u16* __restrict__ Vtb,
                                                 u16* __restrict__ attnb) {
    __shared__ __align__(16) u16 KV[4][2][4096];  // [slot][K/V][64x64]
    int tid = threadIdx.x;
    int w = tid >> 6, lane = tid & 63, quad = lane >> 4, l16 = lane & 15;
    int L = blockIdx.x;
    int bh = ((L & 7) << 2) | ((L >> 3) & 3);
    int pr = L >> 5;  // 0..15
    int qta = pr, qtb = 31 - pr;
    const u16* Qp = Qb + (size_t)bh * 131072;
    const u16* Kp = Kb + (size_t)bh * 131072;
    const u16* Vp = Vtb + (size_t)bh * 131072;

    // staging constants (XOR-swizzled chunk layout, wave-uniform LDS base)
    int r0 = tid >> 3, c0 = ((tid & 7) ^ (r0 & 7)) * 8;
    int f1 = 256 + tid;
    int r1 = f1 >> 3, c1 = ((f1 & 7) ^ (r1 & 7)) * 8;
    int kOff0 = r0 * 64 + c0, kOff1 = r1 * 64 + c1;
    int vOff0 = r0 * 2048 + c0, vOff1 = r1 * 2048 + c1;
    int wb = (tid & ~63) * 8;

    // Q fragments for both halves (kept in registers the whole kernel)
    int qrowa = qta * 64 + w * 16 + l16;
    int qrowb = qtb * 64 + w * 16 + l16;
    short8 qa0 = *(const short8*)&Qp[(size_t)qrowa * 64 + quad * 8];
    short8 qa1 = *(const short8*)&Qp[(size_t)qrowa * 64 + 32 + quad * 8];
    short8 qb0 = *(const short8*)&Qp[(size_t)qrowb * 64 + quad * 8];
    short8 qb1 = *(const short8*)&Qp[(size_t)qrowb * 64 + 32 + quad * 8];

    int na = qta + 1;
    int n = na + qtb + 1;  // always 33

    auto stage = [&](int j) {  // j pre-clamped to [0, n)
        int kt = (j < na) ? j : (j - na);
        u16* Ks = (u16*)KV[j & 3][0];
        u16* Vs = (u16*)KV[j & 3][1];
        const u16* kp = Kp + (size_t)kt * 4096;
        const u16* vp = Vp + (size_t)kt * 64;
        async_cp16(kp + kOff0, Ks + wb);
        async_cp16(kp + kOff1, Ks + 2048 + wb);
        async_cp16(vp + vOff0, Vs + wb);
        async_cp16(vp + vOff1, Vs + 2048 + wb);
    };

    floatx4 accO[4] = {};
    float m_run = -__builtin_inff(), l_run = 0.f;
    int sw = l16 & 7;
    int kt = 0, qt = qta, q0 = qta * 64;
    short8 cq0 = qa0, cq1 = qa1;
    int b = bh >> 4, h = bh & 15;

    stage(0); stage(1); stage(2);

    for (int j = 0; j < n; ++j) {
        asm volatile("s_waitcnt vmcnt(8)" ::: "memory");  // oldest stage landed
        asm volatile("s_barrier" ::: "memory");           // cross-wave visibility
        {
            int jn = j + 3;
            stage(jn < n ? jn : n - 1);  // uniform 4 loads/iter (clamp = redundant reload)
        }
        const u16* Ks = (const u16*)KV[j & 3][0];
        const u16* Vs = (const u16*)KV[j & 3][1];

        // S^T = K Q^T : lane holds S[qrow=l16][key = kt*64 + nt*16 + quad*4 + r]
        floatx4 sa[4] = {};
#pragma unroll
        for (int nt = 0; nt < 4; ++nt) {
            int rb = (nt * 16 + l16) * 8;
            short8 kfa = *(const short8*)&Ks[(rb + (quad ^ sw)) * 8];
            short8 kfb = *(const short8*)&Ks[(rb + ((4 + quad) ^ sw)) * 8];
            sa[nt] = MFMA16(kfa, cq0, sa[nt]);
            sa[nt] = MFMA16(kfb, cq1, sa[nt]);
        }
        if (kt == qt) {  // diagonal tile: causal mask
            int q_abs = q0 + w * 16 + l16;
#pragma unroll
            for (int nt = 0; nt < 4; ++nt)
#pragma unroll
                for (int r = 0; r < 4; ++r)
                    if (kt * 64 + nt * 16 + quad * 4 + r > q_abs)
                        sa[nt][r] = -__builtin_inff();
        }
        // online softmax (exp2 domain); q-row fixed per lane, replicated x4
        float v = sa[0][0];
#pragma unroll
        for (int nt = 0; nt < 4; ++nt)
#pragma unroll
            for (int r = 0; r < 4; ++r) v = fmaxf(v, sa[nt][r]);
        v = fmaxf(v, __shfl_xor(v, 16));
        v = fmaxf(v, __shfl_xor(v, 32));
        float m_new = fmaxf(m_run, v);
        float alpha = EXP2(m_run - m_new);
        float p[4][4];
        float rs = 0.f;
#pragma unroll
        for (int nt = 0; nt < 4; ++nt)
#pragma unroll
            for (int r = 0; r < 4; ++r) {
                float e = EXP2(sa[nt][r] - m_new);
                p[nt][r] = e;
                rs += e;
            }
        rs += __shfl_xor(rs, 16);
        rs += __shfl_xor(rs, 32);
        l_run = l_run * alpha + rs;
        m_run = m_new;
        float al[4];
#pragma unroll
        for (int r = 0; r < 4; ++r) al[r] = __shfl(alpha, quad * 4 + r, 16);
#pragma unroll
        for (int dt = 0; dt < 4; ++dt)
#pragma unroll
            for (int r = 0; r < 4; ++r) accO[dt][r] *= al[r];
        // P regs are the K=16 A-frag: pack and accumulate into O
#pragma unroll
        for (int nt = 0; nt < 4; ++nt) {
            union { uint2 u; short4v s; } pf;
            pf.u.x = pkbf(p[nt][0], p[nt][1]);
            pf.u.y = pkbf(p[nt][2], p[nt][3]);
#pragma unroll
            for (int dt = 0; dt < 4; ++dt) {
                int row = dt * 16 + l16;
                int chunk = nt * 2 + (quad >> 1);
                const char* vb2 = (const char*)Vs + row * 128 + ((chunk ^ (row & 7)) * 16) + (quad & 1) * 8;
                short4v vf = *(const short4v*)vb2;
                accO[dt] = PV_MFMA(pf.s, vf, accO[dt]);
            }
        }

        if (kt == qt) {  // end of this half: write O, reset state
            float lbc[4];
#pragma unroll
            for (int r = 0; r < 4; ++r) lbc[r] = __shfl(l_run, quad * 4 + r, 16);
#pragma unroll
            for (int r = 0; r < 4; ++r) {
                float inv = 1.f / lbc[r];
                int q_abs = q0 + w * 16 + quad * 4 + r;
                size_t base = ((size_t)(b * 2048 + q_abs)) * 1024 + h * 64;
#pragma unroll
                for (int dt = 0; dt < 4; ++dt)
                    attnb[base + dt * 16 + l16] = f2b(accO[dt][r] * inv);
            }
#pragma unroll
            for (int dt = 0; dt < 4; ++dt) accO[dt] = floatx4{0.f, 0.f, 0.f, 0.f};
            m_run = -__builtin_inff();
            l_run = 0.f;
            kt = 0;
            qt = qtb;
            q0 = qtb * 64;
            cq0 = qb0;
            cq1 = qb1;
        } else {
            ++kt;
        }
    }
}

// ---------------- launch ----------------

extern "C" void kernel_launch(void* const* d_in, const int* in_sizes, int n_in,
                              void* d_out, int out_size, void* d_ws, size_t ws_size,
                              hipStream_t stream) {
    const float* x     = (const float*)d_in[0];
    const float* W_qkv = (const float*)d_in[1];
    const float* b_qkv = (const float*)d_in[2];
    const float* W_out = (const float*)d_in[3];
    const float* b_out = (const float*)d_in[4];
    float* out = (float*)d_out;

    char* p = (char*)d_ws;
    u16* xb    = (u16*)p; p += (size_t)4096 * 1024 * 2;     // 8 MB (reused as attn out)
    u16* wqkvT = (u16*)p; p += (size_t)3072 * 1024 * 2;     // 6 MB
    u16* woutT = (u16*)p; p += (size_t)1024 * 1024 * 2;     // 2 MB
    u16* Qb    = (u16*)p; p += (size_t)32 * 2048 * 64 * 2;  // 8 MB (pre-scaled, exp2 domain)
    u16* Kb    = (u16*)p; p += (size_t)32 * 2048 * 64 * 2;  // 8 MB
    u16* Vtb   = (u16*)p; p += (size_t)32 * 64 * 2048 * 2;  // 8 MB [bh][d][s]
    u16* attnb = xb;  // xb dead after k_qkv_gemm

    k_f32_to_bf16<<<(4096 * 1024 / 8) / 256, 256, 0, stream>>>(x, xb, 4096 * 1024 / 8);
    dim3 tb(32, 8);
    k_transpose_to_bf16<<<dim3(3072 / 32, 1024 / 32), tb, 0, stream>>>(W_qkv, wqkvT, 1024, 3072);
    k_transpose_to_bf16<<<dim3(1024 / 32, 1024 / 32), tb, 0, stream>>>(W_out, woutT, 1024, 1024);
    k_qkv_gemm<<<dim3(24, 32), 256, 0, stream>>>(xb, wqkvT, b_qkv, Qb, Kb, Vtb);
    k_attn<<<512, 256, 0, stream>>>(Qb, Kb, Vtb, attnb);
    k_out_gemm<<<dim3(8, 64), 256, 0, stream>>>(attnb, woutT, b_out, out);
}

// Round 5
// 189.773 us; speedup vs baseline: 1.6240x; 1.0228x over previous
//
#include <hip/hip_runtime.h>
#include <hip/hip_bf16.h>
#include <cstdint>
#include <cstddef>

// ---------------------------------------------------------------------------
// MultiHeadAttention  B=2 S=2048 E=1024 H=16 D=64 causal, bf16 MFMA path.
// conv -> qkv gemm128 -> flash attn (ring-4 LDS, raw s_barrier + vmcnt(8),
// MERGED q-tile pair per block, lane-local softmax via swapped PV operands)
// -> out gemm 64x128.
// ---------------------------------------------------------------------------

typedef unsigned short u16;
typedef __attribute__((ext_vector_type(8))) short short8;
typedef __attribute__((ext_vector_type(4))) short short4v;
typedef __attribute__((ext_vector_type(4))) float floatx4;

#define MFMA16(a, b, c) __builtin_amdgcn_mfma_f32_16x16x32_bf16((a), (b), (c), 0, 0, 0)

#if __has_builtin(__builtin_amdgcn_mfma_f32_16x16x16_bf16)
#define PV_MFMA(a, b, c) __builtin_amdgcn_mfma_f32_16x16x16_bf16((a), (b), (c), 0, 0, 0)
#elif __has_builtin(__builtin_amdgcn_mfma_f32_16x16x16bf16_1k)
#define PV_MFMA(a, b, c) __builtin_amdgcn_mfma_f32_16x16x16bf16_1k((a), (b), (c), 0, 0, 0)
#else
static __device__ __forceinline__ floatx4 pv_mfma_asm(short4v a, short4v b, floatx4 c) {
    asm volatile("v_mfma_f32_16x16x16_bf16 %0, %1, %2, %0" : "+v"(c) : "v"(a), "v"(b));
    return c;
}
#define PV_MFMA(a, b, c) pv_mfma_asm((a), (b), (c))
#endif

#if __has_builtin(__builtin_amdgcn_exp2f)
#define EXP2(x) __builtin_amdgcn_exp2f(x)
#else
#define EXP2(x) exp2f(x)
#endif

#define QSCALE 0.18033688011f  // 0.125 * log2(e)

static __device__ __forceinline__ u16 f2b(float f) {
    union { float f; uint32_t u; } v; v.f = f;
    return (u16)((v.u + 0x7fffu + ((v.u >> 16) & 1u)) >> 16);  // RNE
}

static __device__ __forceinline__ uint32_t pkbf(float lo, float hi) {
    union { float f; uint32_t u; } a, b; a.f = lo; b.f = hi;
    return __builtin_amdgcn_perm(b.u + 0x8000u, a.u + 0x8000u, 0x07060302u);
}

static __device__ __forceinline__ void async_cp16(const u16* g, u16* lds_wave_base) {
    __builtin_amdgcn_global_load_lds((__attribute__((address_space(1))) void*)g,
                                     (__attribute__((address_space(3))) void*)lds_wave_base,
                                     16, 0, 0);
}

// ---------------- conversion kernels ----------------

__global__ __launch_bounds__(256) void k_f32_to_bf16(const float* __restrict__ src,
                                                     u16* __restrict__ dst, int n8) {
    int g = blockIdx.x * 256 + threadIdx.x;
    if (g >= n8) return;
    const float4* s = (const float4*)src + (size_t)g * 2;
    float4 f0 = s[0];
    float4 f1 = s[1];
    alignas(16) u16 r[8] = {f2b(f0.x), f2b(f0.y), f2b(f0.z), f2b(f0.w),
                            f2b(f1.x), f2b(f1.y), f2b(f1.z), f2b(f1.w)};
    *(uint4*)(dst + (size_t)g * 8) = *(const uint4*)r;
}

__global__ __launch_bounds__(256) void k_transpose_to_bf16(const float* __restrict__ src,
                                                           u16* __restrict__ dst,
                                                           int R, int C) {
    __shared__ float t[32][33];
    int tx = threadIdx.x, ty = threadIdx.y;
    int c0 = blockIdx.x * 32, r0 = blockIdx.y * 32;
#pragma unroll
    for (int i = 0; i < 4; ++i)
        t[ty + i * 8][tx] = src[(size_t)(r0 + ty + i * 8) * C + c0 + tx];
    __syncthreads();
#pragma unroll
    for (int i = 0; i < 4; ++i)
        dst[(size_t)(c0 + ty + i * 8) * R + r0 + tx] = f2b(t[tx][ty + i * 8]);
}

// ---------------- qkv GEMM 128x128 (m97 structure + XOR swizzle) ------------

__global__ __launch_bounds__(256) void k_qkv_gemm(const u16* __restrict__ A,
                                                  const u16* __restrict__ Bt,
                                                  const float* __restrict__ bias,
                                                  u16* __restrict__ Qb,
                                                  u16* __restrict__ Kb,
                                                  u16* __restrict__ Vtb) {
    __shared__ __align__(16) u16 As[128 * 64];
    __shared__ __align__(16) u16 Bs[128 * 64];
    int tid = threadIdx.x;
    int w = tid >> 6, lane = tid & 63, quad = lane >> 4, l16 = lane & 15;
    int wm = w >> 1, wn = w & 1;
    int m0 = blockIdx.y * 128, n0 = blockIdx.x * 128;
    int wb8 = (tid & ~63) * 8;
    floatx4 acc[4][4] = {};

    for (int kt = 0; kt < 16; ++kt) {
#pragma unroll
        for (int i = 0; i < 4; ++i) {
            int f = i * 256 + tid;
            int r = f >> 3, c = (f & 7) ^ (r & 7);
            async_cp16(&A[(size_t)(m0 + r) * 1024 + kt * 64 + c * 8], &As[i * 2048 + wb8]);
        }
#pragma unroll
        for (int i = 0; i < 4; ++i) {
            int f = i * 256 + tid;
            int r = f >> 3, c = (f & 7) ^ (r & 7);
            async_cp16(&Bt[(size_t)(n0 + r) * 1024 + kt * 64 + c * 8], &Bs[i * 2048 + wb8]);
        }
        __syncthreads();
#pragma unroll
        for (int ks = 0; ks < 2; ++ks) {
            short8 af[4], bf[4];
            int sw = l16 & 7;
#pragma unroll
            for (int mt = 0; mt < 4; ++mt)
                af[mt] = *(const short8*)&As[((wm * 64 + mt * 16 + l16) * 8 + ((ks * 4 + quad) ^ sw)) * 8];
#pragma unroll
            for (int nt = 0; nt < 4; ++nt)
                bf[nt] = *(const short8*)&Bs[((wn * 64 + nt * 16 + l16) * 8 + ((ks * 4 + quad) ^ sw)) * 8];
#pragma unroll
            for (int mt = 0; mt < 4; ++mt)
#pragma unroll
                for (int nt = 0; nt < 4; ++nt)
                    acc[mt][nt] = MFMA16(af[mt], bf[nt], acc[mt][nt]);
        }
        __syncthreads();
    }

    int region = n0 >> 10;  // 0=Q 1=K 2=V
    if (region == 2) {
#pragma unroll
        for (int mt = 0; mt < 4; ++mt)
#pragma unroll
            for (int nt = 0; nt < 4; ++nt) {
                int n_abs = n0 + wn * 64 + nt * 16 + l16;
                int e = n_abs & 1023, h = e >> 6, d = e & 63;
                float vb = bias[n_abs];
                int mrow = m0 + wm * 64 + mt * 16 + quad * 4;
                int b = mrow >> 11, s0 = mrow & 2047;
                uint2 val;
                val.x = pkbf(acc[mt][nt][0] + vb, acc[mt][nt][1] + vb);
                val.y = pkbf(acc[mt][nt][2] + vb, acc[mt][nt][3] + vb);
                *(uint2*)&Vtb[((size_t)(b * 16 + h) * 64 + d) * 2048 + s0] = val;
            }
    } else {
        u16* dst = region == 0 ? Qb : Kb;
        float scl = region == 0 ? QSCALE : 1.0f;
#pragma unroll
        for (int mt = 0; mt < 4; ++mt)
#pragma unroll
            for (int nt = 0; nt < 4; ++nt)
#pragma unroll
                for (int r = 0; r < 4; ++r) {
                    int m_abs = m0 + wm * 64 + mt * 16 + quad * 4 + r;
                    int n_abs = n0 + wn * 64 + nt * 16 + l16;
                    float val = (acc[mt][nt][r] + bias[n_abs]) * scl;
                    int e = n_abs & 1023, h = e >> 6, d = e & 63;
                    int b = m_abs >> 11, s = m_abs & 2047;
                    dst[((size_t)(b * 16 + h) * 2048 + s) * 64 + d] = f2b(val);
                }
    }
}

// ---------------- out GEMM 64M x 128N (grid 512 = 2 blocks/CU) -------------

__global__ __launch_bounds__(256) void k_out_gemm(const u16* __restrict__ A,
                                                  const u16* __restrict__ Bt,
                                                  const float* __restrict__ bias,
                                                  float* __restrict__ out) {
    __shared__ __align__(16) u16 As[64 * 64];
    __shared__ __align__(16) u16 Bs[128 * 64];
    int tid = threadIdx.x;
    int w = tid >> 6, lane = tid & 63, quad = lane >> 4, l16 = lane & 15;
    int wm = w >> 1, wn = w & 1;
    int m0 = blockIdx.y * 64, n0 = blockIdx.x * 128;
    int wb8 = (tid & ~63) * 8;
    floatx4 acc[2][4] = {};

    for (int kt = 0; kt < 16; ++kt) {
#pragma unroll
        for (int i = 0; i < 2; ++i) {
            int f = i * 256 + tid;
            int r = f >> 3, c = (f & 7) ^ (r & 7);
            async_cp16(&A[(size_t)(m0 + r) * 1024 + kt * 64 + c * 8], &As[i * 2048 + wb8]);
        }
#pragma unroll
        for (int i = 0; i < 4; ++i) {
            int f = i * 256 + tid;
            int r = f >> 3, c = (f & 7) ^ (r & 7);
            async_cp16(&Bt[(size_t)(n0 + r) * 1024 + kt * 64 + c * 8], &Bs[i * 2048 + wb8]);
        }
        __syncthreads();
#pragma unroll
        for (int ks = 0; ks < 2; ++ks) {
            short8 af[2], bf[4];
            int sw = l16 & 7;
#pragma unroll
            for (int mt = 0; mt < 2; ++mt)
                af[mt] = *(const short8*)&As[((wm * 32 + mt * 16 + l16) * 8 + ((ks * 4 + quad) ^ sw)) * 8];
#pragma unroll
            for (int nt = 0; nt < 4; ++nt)
                bf[nt] = *(const short8*)&Bs[((wn * 64 + nt * 16 + l16) * 8 + ((ks * 4 + quad) ^ sw)) * 8];
#pragma unroll
            for (int mt = 0; mt < 2; ++mt)
#pragma unroll
                for (int nt = 0; nt < 4; ++nt)
                    acc[mt][nt] = MFMA16(af[mt], bf[nt], acc[mt][nt]);
        }
        __syncthreads();
    }

#pragma unroll
    for (int mt = 0; mt < 2; ++mt)
#pragma unroll
        for (int nt = 0; nt < 4; ++nt)
#pragma unroll
            for (int r = 0; r < 4; ++r) {
                int m_abs = m0 + wm * 32 + mt * 16 + quad * 4 + r;
                int n_abs = n0 + wn * 64 + nt * 16 + l16;
                out[(size_t)m_abs * 1024 + n_abs] = acc[mt][nt][r] + bias[n_abs];
            }
}

// ---------------- flash attention: merged pair + lane-local softmax ---------
// grid 512: bh = (L&7)*4 + (L>>3)&3 (4 heads/XCD -> K/V L2-resident).
// idx=(L>>5): pr = idx<8 ? idx : 23-idx  -> CU pairs sum to 49 iters (balanced
// under round-robin). Block streams K/V tiles kt=0..31-pr ONCE, accumulating
// q-tile qta=pr (while kt<=qta) and qtb=31-pr simultaneously; K/V LDS frags
// shared by both tiles. PV uses swapped operands (A=V^T frag, B=P frag) so O
// lands with q on l16 -> alpha & 1/l are lane-local (NO cross-lane shfl on
// the softmax->rescale path). Ring-4 LDS, raw s_barrier + vmcnt(8).

__global__ __launch_bounds__(256, 2) void k_attn(const u16* __restrict__ Qb,
                                                 const u16* __restrict__ Kb,
                                                 const u16* __restrict__ Vtb,
                                                 u16* __restrict__ attnb) {
    __shared__ __align__(16) u16 KV[4][2][4096];  // [slot][K/V][64x64]
    int tid = threadIdx.x;
    int w = tid >> 6, lane = tid & 63, quad = lane >> 4, l16 = lane & 15;
    int L = blockIdx.x;
    int bh = ((L & 7) << 2) | ((L >> 3) & 3);
    int idx = (L >> 5) & 15;
    int pr = idx < 8 ? idx : 23 - idx;
    int qta = pr, qtb = 31 - pr;
    const u16* Qp = Qb + (size_t)bh * 131072;
    const u16* Kp = Kb + (size_t)bh * 131072;
    const u16* Vp = Vtb + (size_t)bh * 131072;
    int b = bh >> 4, h = bh & 15;

    // staging constants (XOR-swizzled chunk layout, wave-uniform LDS base)
    int r0 = tid >> 3, c0 = ((tid & 7) ^ (r0 & 7)) * 8;
    int f1 = 256 + tid;
    int r1 = f1 >> 3, c1 = ((f1 & 7) ^ (r1 & 7)) * 8;
    int kOff0 = r0 * 64 + c0, kOff1 = r1 * 64 + c1;
    int vOff0 = r0 * 2048 + c0, vOff1 = r1 * 2048 + c1;
    int wb = (tid & ~63) * 8;

    // Q fragments for both tiles (registers for the whole kernel)
    int qrowa = qta * 64 + w * 16 + l16;
    int qrowb = qtb * 64 + w * 16 + l16;
    short8 qa0 = *(const short8*)&Qp[(size_t)qrowa * 64 + quad * 8];
    short8 qa1 = *(const short8*)&Qp[(size_t)qrowa * 64 + 32 + quad * 8];
    short8 qb0 = *(const short8*)&Qp[(size_t)qrowb * 64 + quad * 8];
    short8 qb1 = *(const short8*)&Qp[(size_t)qrowb * 64 + 32 + quad * 8];

    int n = qtb + 1;

    auto stage = [&](int j) {
        u16* Ks = (u16*)KV[j & 3][0];
        u16* Vs = (u16*)KV[j & 3][1];
        const u16* kp = Kp + (size_t)j * 4096;
        const u16* vp = Vp + (size_t)j * 64;
        async_cp16(kp + kOff0, Ks + wb);
        async_cp16(kp + kOff1, Ks + 2048 + wb);
        async_cp16(vp + vOff0, Vs + wb);
        async_cp16(vp + vOff1, Vs + 2048 + wb);
    };

    floatx4 accA[4] = {}, accB[4] = {};
    float ma = -__builtin_inff(), la = 0.f;
    float mb = -__builtin_inff(), lb = 0.f;
    int sw = l16 & 7;

    stage(0); stage(1); stage(2);

    for (int kt = 0; kt < n; ++kt) {
        asm volatile("s_waitcnt vmcnt(8)" ::: "memory");  // oldest stage landed
        asm volatile("s_barrier" ::: "memory");           // all waves done with slot kt-1
        {
            int jn = kt + 3;
            stage(jn < n ? jn : n - 1);  // uniform 4 loads/iter
        }
        const u16* Ks = (const u16*)KV[kt & 3][0];
        const u16* Vs = (const u16*)KV[kt & 3][1];

        // shared fragments: K (B-frag of QK^T) and V^T (A-frag of PV)
        short8 kfa[4], kfb[4];
#pragma unroll
        for (int nt = 0; nt < 4; ++nt) {
            int rb = (nt * 16 + l16) * 8;
            kfa[nt] = *(const short8*)&Ks[(rb + (quad ^ sw)) * 8];
            kfb[nt] = *(const short8*)&Ks[(rb + ((4 + quad) ^ sw)) * 8];
        }
        short4v vf[4][4];
#pragma unroll
        for (int dt = 0; dt < 4; ++dt) {
            const char* rowb = (const char*)Vs + (dt * 16 + l16) * 128 + (quad & 1) * 8;
#pragma unroll
            for (int nt = 0; nt < 4; ++nt) {
                int chunk = nt * 2 + (quad >> 1);
                vf[nt][dt] = *(const short4v*)(rowb + ((chunk ^ sw) * 16));
            }
        }

        auto tile_step = [&](short8 qf0, short8 qf1, int qt_this, float& mr, float& lr,
                             floatx4* accO) {
            // S^T: lane holds S[q = l16-row of this wave][key = kt*64+nt*16+quad*4+r]
            floatx4 sa[4] = {};
#pragma unroll
            for (int nt = 0; nt < 4; ++nt) {
                sa[nt] = MFMA16(kfa[nt], qf0, sa[nt]);
                sa[nt] = MFMA16(kfb[nt], qf1, sa[nt]);
            }
            if (kt == qt_this) {  // diagonal tile: causal mask
                int q_abs = qt_this * 64 + w * 16 + l16;
#pragma unroll
                for (int nt = 0; nt < 4; ++nt)
#pragma unroll
                    for (int r = 0; r < 4; ++r)
                        if (kt * 64 + nt * 16 + quad * 4 + r > q_abs)
                            sa[nt][r] = -__builtin_inff();
            }
            // online softmax (exp2 domain); all stats lane-local in l16's q-row
            float v = sa[0][0];
#pragma unroll
            for (int nt = 0; nt < 4; ++nt)
#pragma unroll
                for (int r = 0; r < 4; ++r) v = fmaxf(v, sa[nt][r]);
            v = fmaxf(v, __shfl_xor(v, 16));
            v = fmaxf(v, __shfl_xor(v, 32));
            float m_new = fmaxf(mr, v);
            float alpha = EXP2(mr - m_new);
            float p[4][4];
            float rs = 0.f;
#pragma unroll
            for (int nt = 0; nt < 4; ++nt)
#pragma unroll
                for (int r = 0; r < 4; ++r) {
                    float e = EXP2(sa[nt][r] - m_new);
                    p[nt][r] = e;
                    rs += e;
                }
            rs += __shfl_xor(rs, 16);
            rs += __shfl_xor(rs, 32);
            lr = lr * alpha + rs;
            mr = m_new;
#pragma unroll
            for (int dt = 0; dt < 4; ++dt)
#pragma unroll
                for (int r = 0; r < 4; ++r) accO[dt][r] *= alpha;  // lane-local!
            // PV swapped: D = (V^T frag) x (P frag) -> O[q=l16][d=dt*16+quad*4+r]
#pragma unroll
            for (int nt = 0; nt < 4; ++nt) {
                union { uint2 u; short4v s; } pf;
                pf.u.x = pkbf(p[nt][0], p[nt][1]);
                pf.u.y = pkbf(p[nt][2], p[nt][3]);
#pragma unroll
                for (int dt = 0; dt < 4; ++dt)
                    accO[dt] = PV_MFMA(vf[nt][dt], pf.s, accO[dt]);
            }
        };

        tile_step(qb0, qb1, qtb, mb, lb, accB);
        if (kt <= qta) tile_step(qa0, qa1, qta, ma, la, accA);
    }

    // epilogue: O[q=l16][d=dt*16+quad*4+r], inv lane-local -> 8B stores
    auto epilogue = [&](int qt_this, float lr, const floatx4* accO) {
        int q_abs = qt_this * 64 + w * 16 + l16;
        float inv = 1.f / lr;
        size_t base = ((size_t)(b * 2048 + q_abs)) * 1024 + h * 64;
#pragma unroll
        for (int dt = 0; dt < 4; ++dt) {
            uint2 val;
            val.x = pkbf(accO[dt][0] * inv, accO[dt][1] * inv);
            val.y = pkbf(accO[dt][2] * inv, accO[dt][3] * inv);
            *(uint2*)&attnb[base + dt * 16 + quad * 4] = val;
        }
    };
    epilogue(qta, la, accA);
    epilogue(qtb, lb, accB);
}

// ---------------- launch ----------------

extern "C" void kernel_launch(void* const* d_in, const int* in_sizes, int n_in,
                              void* d_out, int out_size, void* d_ws, size_t ws_size,
                              hipStream_t stream) {
    const float* x     = (const float*)d_in[0];
    const float* W_qkv = (const float*)d_in[1];
    const float* b_qkv = (const float*)d_in[2];
    const float* W_out = (const float*)d_in[3];
    const float* b_out = (const float*)d_in[4];
    float* out = (float*)d_out;

    char* p = (char*)d_ws;
    u16* xb    = (u16*)p; p += (size_t)4096 * 1024 * 2;     // 8 MB (reused as attn out)
    u16* wqkvT = (u16*)p; p += (size_t)3072 * 1024 * 2;     // 6 MB
    u16* woutT = (u16*)p; p += (size_t)1024 * 1024 * 2;     // 2 MB
    u16* Qb    = (u16*)p; p += (size_t)32 * 2048 * 64 * 2;  // 8 MB (pre-scaled, exp2 domain)
    u16* Kb    = (u16*)p; p += (size_t)32 * 2048 * 64 * 2;  // 8 MB
    u16* Vtb   = (u16*)p; p += (size_t)32 * 64 * 2048 * 2;  // 8 MB [bh][d][s]
    u16* attnb = xb;  // xb dead after k_qkv_gemm

    k_f32_to_bf16<<<(4096 * 1024 / 8) / 256, 256, 0, stream>>>(x, xb, 4096 * 1024 / 8);
    dim3 tb(32, 8);
    k_transpose_to_bf16<<<dim3(3072 / 32, 1024 / 32), tb, 0, stream>>>(W_qkv, wqkvT, 1024, 3072);
    k_transpose_to_bf16<<<dim3(1024 / 32, 1024 / 32), tb, 0, stream>>>(W_out, woutT, 1024, 1024);
    k_qkv_gemm<<<dim3(24, 32), 256, 0, stream>>>(xb, wqkvT, b_qkv, Qb, Kb, Vtb);
    k_attn<<<512, 256, 0, stream>>>(Qb, Kb, Vtb, attnb);
    k_out_gemm<<<dim3(8, 64), 256, 0, stream>>>(attnb, woutT, b_out, out);
}

// Round 6
// 179.767 us; speedup vs baseline: 1.7144x; 1.0557x over previous
//
#include <hip/hip_runtime.h>
#include <hip/hip_bf16.h>
#include <cstdint>
#include <cstddef>

// ---------------------------------------------------------------------------
// MultiHeadAttention  B=2 S=2048 E=1024 H=16 D=64 causal, bf16 MFMA path.
// k_prep (fused convert+transposes) -> qkv gemm (ring-3 BK=32 pipeline) ->
// flash attn (ring-4, merged q-tile pair, lane-local softmax) ->
// out gemm (ring-3 BK=32).  Raw s_barrier + fine vmcnt everywhere: prefetch
// loads are never drained by a barrier.
// ---------------------------------------------------------------------------

typedef unsigned short u16;
typedef __attribute__((ext_vector_type(8))) short short8;
typedef __attribute__((ext_vector_type(4))) short short4v;
typedef __attribute__((ext_vector_type(4))) float floatx4;

#define MFMA16(a, b, c) __builtin_amdgcn_mfma_f32_16x16x32_bf16((a), (b), (c), 0, 0, 0)

#if __has_builtin(__builtin_amdgcn_mfma_f32_16x16x16_bf16)
#define PV_MFMA(a, b, c) __builtin_amdgcn_mfma_f32_16x16x16_bf16((a), (b), (c), 0, 0, 0)
#elif __has_builtin(__builtin_amdgcn_mfma_f32_16x16x16bf16_1k)
#define PV_MFMA(a, b, c) __builtin_amdgcn_mfma_f32_16x16x16bf16_1k((a), (b), (c), 0, 0, 0)
#else
static __device__ __forceinline__ floatx4 pv_mfma_asm(short4v a, short4v b, floatx4 c) {
    asm volatile("v_mfma_f32_16x16x16_bf16 %0, %1, %2, %0" : "+v"(c) : "v"(a), "v"(b));
    return c;
}
#define PV_MFMA(a, b, c) pv_mfma_asm((a), (b), (c))
#endif

#if __has_builtin(__builtin_amdgcn_exp2f)
#define EXP2(x) __builtin_amdgcn_exp2f(x)
#else
#define EXP2(x) exp2f(x)
#endif

#define QSCALE 0.18033688011f  // 0.125 * log2(e)

static __device__ __forceinline__ u16 f2b(float f) {
    union { float f; uint32_t u; } v; v.f = f;
    return (u16)((v.u + 0x7fffu + ((v.u >> 16) & 1u)) >> 16);  // RNE
}

static __device__ __forceinline__ uint32_t pkbf(float lo, float hi) {
    union { float f; uint32_t u; } a, b; a.f = lo; b.f = hi;
    return __builtin_amdgcn_perm(b.u + 0x8000u, a.u + 0x8000u, 0x07060302u);
}

static __device__ __forceinline__ void async_cp16(const u16* g, u16* lds_wave_base) {
    __builtin_amdgcn_global_load_lds((__attribute__((address_space(1))) void*)g,
                                     (__attribute__((address_space(3))) void*)lds_wave_base,
                                     16, 0, 0);
}

// ---------------- fused prep: x->bf16, W_qkv^T->bf16, W_out^T->bf16 ---------
// blocks [0,2048): x convert; [2048,5120): W_qkv transpose; [5120,6144): W_out.

__global__ __launch_bounds__(256) void k_prep(const float* __restrict__ x,
                                              const float* __restrict__ Wq,
                                              const float* __restrict__ Wo,
                                              u16* __restrict__ xb,
                                              u16* __restrict__ wqkvT,
                                              u16* __restrict__ woutT) {
    int bx = blockIdx.x, tid = threadIdx.x;
    if (bx < 2048) {
        int g = bx * 256 + tid;
        const float4* s = (const float4*)x + (size_t)g * 2;
        float4 f0 = s[0], f1 = s[1];
        uint4 r;
        r.x = pkbf(f0.x, f0.y);
        r.y = pkbf(f0.z, f0.w);
        r.z = pkbf(f1.x, f1.y);
        r.w = pkbf(f1.z, f1.w);
        *(uint4*)(xb + (size_t)g * 8) = r;
        return;
    }
    __shared__ float t[32][33];
    const float* src;
    u16* dst;
    int R, C, b;
    if (bx < 5120) { b = bx - 2048; src = Wq; dst = wqkvT; R = 1024; C = 3072; }
    else           { b = bx - 5120; src = Wo; dst = woutT; R = 1024; C = 1024; }
    int nbx = C >> 5;
    int yq = b / nbx, xq = b - yq * nbx;
    int c0 = xq * 32, r0 = yq * 32;
    int tx = tid & 31, ty = tid >> 5;
#pragma unroll
    for (int i = 0; i < 4; ++i)
        t[ty + i * 8][tx] = src[(size_t)(r0 + ty + i * 8) * C + c0 + tx];
    __syncthreads();
#pragma unroll
    for (int i = 0; i < 4; ++i)
        dst[(size_t)(c0 + ty + i * 8) * R + r0 + tx] = f2b(t[tx][ty + i * 8]);
}

// ---------------- qkv GEMM: 128x128, BK=32, ring-3 pipeline -----------------
// 256 thr = 4 waves (2x2), wave = 64x64 = 4x4 MFMA tiles, one MFMA K-step per
// iter (K=32). LDS rows of 32 u16 = 64 B; a wave's fragment read covers 16
// contiguous rows = contiguous 1 KB -> conflict-free, no swizzle needed.
// Pipeline: wait vmcnt(4) [tile kt landed; kt+1 in flight] -> s_barrier ->
// stage slot (kt+2)%3 [safe: all waves done with kt-1] -> compute kt.

__global__ __launch_bounds__(256, 3) void k_qkv_gemm(const u16* __restrict__ A,
                                                     const u16* __restrict__ Bt,
                                                     const float* __restrict__ bias,
                                                     u16* __restrict__ Qb,
                                                     u16* __restrict__ Kb,
                                                     u16* __restrict__ Vtb) {
    __shared__ __align__(16) u16 As[3][128 * 32];
    __shared__ __align__(16) u16 Bs[3][128 * 32];
    int tid = threadIdx.x;
    int w = tid >> 6, lane = tid & 63, quad = lane >> 4, l16 = lane & 15;
    int wm = w >> 1, wn = w & 1;
    int m0 = blockIdx.y * 128, n0 = blockIdx.x * 128;
    int wb = (tid & ~63) * 8;  // wave-uniform LDS base (u16 units)

    // staging source rows (LDS flat byte offset f*16 == row-major (f>>2, f&3))
    int ra0 = tid >> 2, ca0 = (tid & 3) * 8;
    int ra1 = (256 + tid) >> 2, ca1 = (tid & 3) * 8;
    const u16* A0 = &A[(size_t)(m0 + ra0) * 1024 + ca0];
    const u16* A1 = &A[(size_t)(m0 + ra1) * 1024 + ca1];
    const u16* B0 = &Bt[(size_t)(n0 + ra0) * 1024 + ca0];
    const u16* B1 = &Bt[(size_t)(n0 + ra1) * 1024 + ca1];

    auto stage = [&](int src_kt, int slot) {
        int ko = src_kt * 32;
        async_cp16(A0 + ko, &As[slot][wb]);
        async_cp16(A1 + ko, &As[slot][2048 + wb]);
        async_cp16(B0 + ko, &Bs[slot][wb]);
        async_cp16(B1 + ko, &Bs[slot][2048 + wb]);
    };

    floatx4 acc[4][4] = {};
    stage(0, 0);
    stage(1, 1);

    for (int kt = 0; kt < 32; ++kt) {
        asm volatile("s_waitcnt vmcnt(4)" ::: "memory");  // tile kt landed (mine)
        asm volatile("s_barrier" ::: "memory");           // -> landed for ALL waves
        int jn = kt + 2;
        stage(jn < 32 ? jn : 31, jn % 3);  // uniform 4 loads/iter (tail: dead slot)
        int s = kt % 3;
        short8 af[4], bf[4];
#pragma unroll
        for (int mt = 0; mt < 4; ++mt)
            af[mt] = *(const short8*)&As[s][(wm * 64 + mt * 16 + l16) * 32 + quad * 8];
#pragma unroll
        for (int nt = 0; nt < 4; ++nt)
            bf[nt] = *(const short8*)&Bs[s][(wn * 64 + nt * 16 + l16) * 32 + quad * 8];
#pragma unroll
        for (int mt = 0; mt < 4; ++mt)
#pragma unroll
            for (int nt = 0; nt < 4; ++nt)
                acc[mt][nt] = MFMA16(af[mt], bf[nt], acc[mt][nt]);
    }

    int region = n0 >> 10;  // 0=Q 1=K 2=V
    if (region == 2) {
#pragma unroll
        for (int mt = 0; mt < 4; ++mt)
#pragma unroll
            for (int nt = 0; nt < 4; ++nt) {
                int n_abs = n0 + wn * 64 + nt * 16 + l16;
                int e = n_abs & 1023, h = e >> 6, d = e & 63;
                float vb = bias[n_abs];
                int mrow = m0 + wm * 64 + mt * 16 + quad * 4;
                int b = mrow >> 11, s0 = mrow & 2047;
                uint2 val;
                val.x = pkbf(acc[mt][nt][0] + vb, acc[mt][nt][1] + vb);
                val.y = pkbf(acc[mt][nt][2] + vb, acc[mt][nt][3] + vb);
                *(uint2*)&Vtb[((size_t)(b * 16 + h) * 64 + d) * 2048 + s0] = val;
            }
    } else {
        u16* dst = region == 0 ? Qb : Kb;
        float scl = region == 0 ? QSCALE : 1.0f;
#pragma unroll
        for (int mt = 0; mt < 4; ++mt)
#pragma unroll
            for (int nt = 0; nt < 4; ++nt)
#pragma unroll
                for (int r = 0; r < 4; ++r) {
                    int m_abs = m0 + wm * 64 + mt * 16 + quad * 4 + r;
                    int n_abs = n0 + wn * 64 + nt * 16 + l16;
                    float val = (acc[mt][nt][r] + bias[n_abs]) * scl;
                    int e = n_abs & 1023, h = e >> 6, d = e & 63;
                    int b = m_abs >> 11, s = m_abs & 2047;
                    dst[((size_t)(b * 16 + h) * 2048 + s) * 64 + d] = f2b(val);
                }
    }
}

// ---------------- out GEMM: 64x128, BK=32, ring-3 pipeline ------------------

__global__ __launch_bounds__(256, 4) void k_out_gemm(const u16* __restrict__ A,
                                                     const u16* __restrict__ Bt,
                                                     const float* __restrict__ bias,
                                                     float* __restrict__ out) {
    __shared__ __align__(16) u16 As[3][64 * 32];
    __shared__ __align__(16) u16 Bs[3][128 * 32];
    int tid = threadIdx.x;
    int w = tid >> 6, lane = tid & 63, quad = lane >> 4, l16 = lane & 15;
    int wm = w >> 1, wn = w & 1;
    int m0 = blockIdx.y * 64, n0 = blockIdx.x * 128;
    int wb = (tid & ~63) * 8;

    int ra0 = tid >> 2, ca0 = (tid & 3) * 8;
    int ra1 = (256 + tid) >> 2;
    const u16* A0 = &A[(size_t)(m0 + ra0) * 1024 + ca0];
    const u16* B0 = &Bt[(size_t)(n0 + ra0) * 1024 + ca0];
    const u16* B1 = &Bt[(size_t)(n0 + ra1) * 1024 + ca0];

    auto stage = [&](int src_kt, int slot) {
        int ko = src_kt * 32;
        async_cp16(A0 + ko, &As[slot][wb]);
        async_cp16(B0 + ko, &Bs[slot][wb]);
        async_cp16(B1 + ko, &Bs[slot][2048 + wb]);
    };

    floatx4 acc[2][4] = {};
    stage(0, 0);
    stage(1, 1);

    for (int kt = 0; kt < 32; ++kt) {
        asm volatile("s_waitcnt vmcnt(3)" ::: "memory");
        asm volatile("s_barrier" ::: "memory");
        int jn = kt + 2;
        stage(jn < 32 ? jn : 31, jn % 3);
        int s = kt % 3;
        short8 af[2], bf[4];
#pragma unroll
        for (int mt = 0; mt < 2; ++mt)
            af[mt] = *(const short8*)&As[s][(wm * 32 + mt * 16 + l16) * 32 + quad * 8];
#pragma unroll
        for (int nt = 0; nt < 4; ++nt)
            bf[nt] = *(const short8*)&Bs[s][(wn * 64 + nt * 16 + l16) * 32 + quad * 8];
#pragma unroll
        for (int mt = 0; mt < 2; ++mt)
#pragma unroll
            for (int nt = 0; nt < 4; ++nt)
                acc[mt][nt] = MFMA16(af[mt], bf[nt], acc[mt][nt]);
    }

#pragma unroll
    for (int mt = 0; mt < 2; ++mt)
#pragma unroll
        for (int nt = 0; nt < 4; ++nt)
#pragma unroll
            for (int r = 0; r < 4; ++r) {
                int m_abs = m0 + wm * 32 + mt * 16 + quad * 4 + r;
                int n_abs = n0 + wn * 64 + nt * 16 + l16;
                out[(size_t)m_abs * 1024 + n_abs] = acc[mt][nt][r] + bias[n_abs];
            }
}

// ---------------- flash attention (unchanged from R5) -----------------------
// grid 512: bh = (L&7)*4 + (L>>3)&3 (4 heads/XCD -> K/V L2-resident).
// Merged q-tile pair (pr, 31-pr): K/V tiles streamed once, shared LDS frags.
// PV swapped operands -> lane-local softmax stats. Ring-4 LDS, s_barrier +
// vmcnt(8), depth-3 prefetch.

__global__ __launch_bounds__(256, 2) void k_attn(const u16* __restrict__ Qb,
                                                 const u16* __restrict__ Kb,
                                                 const u16* __restrict__ Vtb,
                                                 u16* __restrict__ attnb) {
    __shared__ __align__(16) u16 KV[4][2][4096];  // [slot][K/V][64x64]
    int tid = threadIdx.x;
    int w = tid >> 6, lane = tid & 63, quad = lane >> 4, l16 = lane & 15;
    int L = blockIdx.x;
    int bh = ((L & 7) << 2) | ((L >> 3) & 3);
    int idx = (L >> 5) & 15;
    int pr = idx < 8 ? idx : 23 - idx;
    int qta = pr, qtb = 31 - pr;
    const u16* Qp = Qb + (size_t)bh * 131072;
    const u16* Kp = Kb + (size_t)bh * 131072;
    const u16* Vp = Vtb + (size_t)bh * 131072;
    int b = bh >> 4, h = bh & 15;

    int r0 = tid >> 3, c0 = ((tid & 7) ^ (r0 & 7)) * 8;
    int f1 = 256 + tid;
    int r1 = f1 >> 3, c1 = ((f1 & 7) ^ (r1 & 7)) * 8;
    int kOff0 = r0 * 64 + c0, kOff1 = r1 * 64 + c1;
    int vOff0 = r0 * 2048 + c0, vOff1 = r1 * 2048 + c1;
    int wb = (tid & ~63) * 8;

    int qrowa = qta * 64 + w * 16 + l16;
    int qrowb = qtb * 64 + w * 16 + l16;
    short8 qa0 = *(const short8*)&Qp[(size_t)qrowa * 64 + quad * 8];
    short8 qa1 = *(const short8*)&Qp[(size_t)qrowa * 64 + 32 + quad * 8];
    short8 qb0 = *(const short8*)&Qp[(size_t)qrowb * 64 + quad * 8];
    short8 qb1 = *(const short8*)&Qp[(size_t)qrowb * 64 + 32 + quad * 8];

    int n = qtb + 1;

    auto stage = [&](int j) {
        u16* Ks = (u16*)KV[j & 3][0];
        u16* Vs = (u16*)KV[j & 3][1];
        const u16* kp = Kp + (size_t)j * 4096;
        const u16* vp = Vp + (size_t)j * 64;
        async_cp16(kp + kOff0, Ks + wb);
        async_cp16(kp + kOff1, Ks + 2048 + wb);
        async_cp16(vp + vOff0, Vs + wb);
        async_cp16(vp + vOff1, Vs + 2048 + wb);
    };

    floatx4 accA[4] = {}, accB[4] = {};
    float ma = -__builtin_inff(), la = 0.f;
    float mb = -__builtin_inff(), lb = 0.f;
    int sw = l16 & 7;

    stage(0); stage(1); stage(2);

    for (int kt = 0; kt < n; ++kt) {
        asm volatile("s_waitcnt vmcnt(8)" ::: "memory");
        asm volatile("s_barrier" ::: "memory");
        {
            int jn = kt + 3;
            stage(jn < n ? jn : n - 1);
        }
        const u16* Ks = (const u16*)KV[kt & 3][0];
        const u16* Vs = (const u16*)KV[kt & 3][1];

        short8 kfa[4], kfb[4];
#pragma unroll
        for (int nt = 0; nt < 4; ++nt) {
            int rb = (nt * 16 + l16) * 8;
            kfa[nt] = *(const short8*)&Ks[(rb + (quad ^ sw)) * 8];
            kfb[nt] = *(const short8*)&Ks[(rb + ((4 + quad) ^ sw)) * 8];
        }
        short4v vf[4][4];
#pragma unroll
        for (int dt = 0; dt < 4; ++dt) {
            const char* rowb = (const char*)Vs + (dt * 16 + l16) * 128 + (quad & 1) * 8;
#pragma unroll
            for (int nt = 0; nt < 4; ++nt) {
                int chunk = nt * 2 + (quad >> 1);
                vf[nt][dt] = *(const short4v*)(rowb + ((chunk ^ sw) * 16));
            }
        }

        auto tile_step = [&](short8 qf0, short8 qf1, int qt_this, float& mr, float& lr,
                             floatx4* accO) {
            floatx4 sa[4] = {};
#pragma unroll
            for (int nt = 0; nt < 4; ++nt) {
                sa[nt] = MFMA16(kfa[nt], qf0, sa[nt]);
                sa[nt] = MFMA16(kfb[nt], qf1, sa[nt]);
            }
            if (kt == qt_this) {
                int q_abs = qt_this * 64 + w * 16 + l16;
#pragma unroll
                for (int nt = 0; nt < 4; ++nt)
#pragma unroll
                    for (int r = 0; r < 4; ++r)
                        if (kt * 64 + nt * 16 + quad * 4 + r > q_abs)
                            sa[nt][r] = -__builtin_inff();
            }
            float v = sa[0][0];
#pragma unroll
            for (int nt = 0; nt < 4; ++nt)
#pragma unroll
                for (int r = 0; r < 4; ++r) v = fmaxf(v, sa[nt][r]);
            v = fmaxf(v, __shfl_xor(v, 16));
            v = fmaxf(v, __shfl_xor(v, 32));
            float m_new = fmaxf(mr, v);
            float alpha = EXP2(mr - m_new);
            float p[4][4];
            float rs = 0.f;
#pragma unroll
            for (int nt = 0; nt < 4; ++nt)
#pragma unroll
                for (int r = 0; r < 4; ++r) {
                    float e = EXP2(sa[nt][r] - m_new);
                    p[nt][r] = e;
                    rs += e;
                }
            rs += __shfl_xor(rs, 16);
            rs += __shfl_xor(rs, 32);
            lr = lr * alpha + rs;
            mr = m_new;
#pragma unroll
            for (int dt = 0; dt < 4; ++dt)
#pragma unroll
                for (int r = 0; r < 4; ++r) accO[dt][r] *= alpha;
#pragma unroll
            for (int nt = 0; nt < 4; ++nt) {
                union { uint2 u; short4v s; } pf;
                pf.u.x = pkbf(p[nt][0], p[nt][1]);
                pf.u.y = pkbf(p[nt][2], p[nt][3]);
#pragma unroll
                for (int dt = 0; dt < 4; ++dt)
                    accO[dt] = PV_MFMA(vf[nt][dt], pf.s, accO[dt]);
            }
        };

        tile_step(qb0, qb1, qtb, mb, lb, accB);
        if (kt <= qta) tile_step(qa0, qa1, qta, ma, la, accA);
    }

    auto epilogue = [&](int qt_this, float lr, const floatx4* accO) {
        int q_abs = qt_this * 64 + w * 16 + l16;
        float inv = 1.f / lr;
        size_t base = ((size_t)(b * 2048 + q_abs)) * 1024 + h * 64;
#pragma unroll
        for (int dt = 0; dt < 4; ++dt) {
            uint2 val;
            val.x = pkbf(accO[dt][0] * inv, accO[dt][1] * inv);
            val.y = pkbf(accO[dt][2] * inv, accO[dt][3] * inv);
            *(uint2*)&attnb[base + dt * 16 + quad * 4] = val;
        }
    };
    epilogue(qta, la, accA);
    epilogue(qtb, lb, accB);
}

// ---------------- launch ----------------

extern "C" void kernel_launch(void* const* d_in, const int* in_sizes, int n_in,
                              void* d_out, int out_size, void* d_ws, size_t ws_size,
                              hipStream_t stream) {
    const float* x     = (const float*)d_in[0];
    const float* W_qkv = (const float*)d_in[1];
    const float* b_qkv = (const float*)d_in[2];
    const float* W_out = (const float*)d_in[3];
    const float* b_out = (const float*)d_in[4];
    float* out = (float*)d_out;

    char* p = (char*)d_ws;
    u16* xb    = (u16*)p; p += (size_t)4096 * 1024 * 2;     // 8 MB (reused as attn out)
    u16* wqkvT = (u16*)p; p += (size_t)3072 * 1024 * 2;     // 6 MB
    u16* woutT = (u16*)p; p += (size_t)1024 * 1024 * 2;     // 2 MB
    u16* Qb    = (u16*)p; p += (size_t)32 * 2048 * 64 * 2;  // 8 MB (pre-scaled, exp2 domain)
    u16* Kb    = (u16*)p; p += (size_t)32 * 2048 * 64 * 2;  // 8 MB
    u16* Vtb   = (u16*)p; p += (size_t)32 * 64 * 2048 * 2;  // 8 MB [bh][d][s]
    u16* attnb = xb;  // xb dead after k_qkv_gemm

    k_prep<<<6144, 256, 0, stream>>>(x, W_qkv, W_out, xb, wqkvT, woutT);
    k_qkv_gemm<<<dim3(24, 32), 256, 0, stream>>>(xb, wqkvT, b_qkv, Qb, Kb, Vtb);
    k_attn<<<512, 256, 0, stream>>>(Qb, Kb, Vtb, attnb);
    k_out_gemm<<<dim3(8, 64), 256, 0, stream>>>(attnb, woutT, b_out, out);
}